// Round 4
// baseline (822.036 us; speedup 1.0000x reference)
//
#include <hip/hip_runtime.h>
#include <hip/hip_bf16.h>

typedef __bf16 bf16_t;
typedef __attribute__((ext_vector_type(8))) __bf16 bf16x8;
typedef __attribute__((ext_vector_type(4))) float floatx4;

#define MFMA16x16x32(a, b, c) __builtin_amdgcn_mfma_f32_16x16x32_bf16((a), (b), (c), 0, 0, 0)

__device__ __forceinline__ void glld16(const bf16_t* g, bf16_t* l) {
    __builtin_amdgcn_global_load_lds(
        (const __attribute__((address_space(1))) unsigned int*)g,
        (__attribute__((address_space(3))) unsigned int*)l,
        16, 0, 0);
}

// Barrier that does NOT drain vmcnt: ds-writes made visible via lgkmcnt(0),
// but in-flight global loads stay outstanding across the barrier (the
// compiler's __syncthreads always drains vmcnt(0) -- round-3's stall).
__device__ __forceinline__ void barrier_keep_vmcnt() {
    asm volatile("s_waitcnt lgkmcnt(0)" ::: "memory");
    __builtin_amdgcn_s_barrier();
    asm volatile("" ::: "memory");
}

// ---------------------------------------------------------------------------
// On-device dtype sniffer (proven round 3): bf16-pair u32 bits 14..7 are the
// low element's exponent, in [112,142] for N(0,1)-ish data; fp32 -> uniform.
// ---------------------------------------------------------------------------
__device__ __forceinline__ bool detect_bf16(const void* hs) {
    const unsigned* u = (const unsigned*)hs;
    int c = 0;
#pragma unroll 8
    for (int i = 0; i < 64; i++) {
        unsigned e = (u[i] >> 7) & 0xFFu;
        c += (e >= 112u && e <= 142u) ? 1 : 0;
    }
    return c >= 32;
}

// ---------------------------------------------------------------------------
// hs -> bf16 copy/convert (fast path). 8 elems/thread.
// ---------------------------------------------------------------------------
__global__ __launch_bounds__(256) void conv_hs(
    const void* __restrict__ src, bf16_t* __restrict__ dst) {
    const bool isbf = detect_bf16(src);
    size_t i8 = ((size_t)blockIdx.x * 256 + threadIdx.x) * 8;
    if (isbf) {
        *(uint4*)(dst + i8) = *(const uint4*)((const bf16_t*)src + i8);
    } else {
        const float* s = (const float*)src + i8;
        float4 f0 = *(const float4*)s;
        float4 f1 = *(const float4*)(s + 4);
        bf16_t tmp[8];
        tmp[0] = (bf16_t)f0.x; tmp[1] = (bf16_t)f0.y;
        tmp[2] = (bf16_t)f0.z; tmp[3] = (bf16_t)f0.w;
        tmp[4] = (bf16_t)f1.x; tmp[5] = (bf16_t)f1.y;
        tmp[6] = (bf16_t)f1.z; tmp[7] = (bf16_t)f1.w;
        *(uint4*)(dst + i8) = *(const uint4*)tmp;
    }
}

// ---------------------------------------------------------------------------
// 64x64-tiled transpose of W cols [coff, coff+64*gridDim.y) into bf16
// Wt[c][r] (dst row-stride 4096). Source dtype sniffed from hs.
// ---------------------------------------------------------------------------
__global__ __launch_bounds__(256) void transpose_w(
    const void* __restrict__ src, bf16_t* __restrict__ dst,
    int coff, const void* __restrict__ hs) {
    const bool isbf = detect_bf16(hs);
    __shared__ bf16_t T[64 * 68];
    const int r0 = blockIdx.x * 64, c0 = blockIdx.y * 64;
    const int t = threadIdx.x;
#pragma unroll
    for (int i = 0; i < 2; i++) {
        int idx = i * 256 + t;
        int r = idx >> 3, c8 = (idx & 7) << 3;
        bf16_t tmp[8];
        if (isbf) {
            *(uint4*)tmp = *(const uint4*)((const bf16_t*)src +
                              (size_t)(r0 + r) * 4096 + coff + c0 + c8);
        } else {
            const float* s = (const float*)src + (size_t)(r0 + r) * 4096 + coff + c0 + c8;
            float4 f0 = *(const float4*)s;
            float4 f1 = *(const float4*)(s + 4);
            tmp[0] = (bf16_t)f0.x; tmp[1] = (bf16_t)f0.y;
            tmp[2] = (bf16_t)f0.z; tmp[3] = (bf16_t)f0.w;
            tmp[4] = (bf16_t)f1.x; tmp[5] = (bf16_t)f1.y;
            tmp[6] = (bf16_t)f1.z; tmp[7] = (bf16_t)f1.w;
        }
        *(uint2*)&T[r * 68 + c8]     = *(const uint2*)&tmp[0];
        *(uint2*)&T[r * 68 + c8 + 4] = *(const uint2*)&tmp[4];
    }
    __syncthreads();
#pragma unroll
    for (int i = 0; i < 2; i++) {
        int idx = i * 256 + t;
        int c = idx >> 3, r8 = (idx & 7) << 3;
        bf16_t tmp[8];
#pragma unroll
        for (int j = 0; j < 8; j++) tmp[j] = T[(r8 + j) * 68 + c];
        *(uint4*)(dst + (size_t)(c0 + c) * 4096 + r0 + r8) = *(const uint4*)tmp;
    }
}

// ---------------------------------------------------------------------------
// FAST-PATH GEMM (m97 structure, bf16 A): C[2048,4096] = A @ Bt^T.
// 256 threads = 4 waves (2x2 of 64x64), 128x128 tile, BK=32, glld16 x4.
// TV: write V^T per head. C32: store dtype sniffed (fp32 out for final GEMM).
// ---------------------------------------------------------------------------
template <bool TV, bool C32>
__global__ __launch_bounds__(256, 2) void gemm_bf16a(
    const bf16_t* __restrict__ A, const bf16_t* __restrict__ Bt,
    void* __restrict__ Cout, const void* __restrict__ hs) {
    constexpr int K = 4096;
    __shared__ bf16_t As[128 * 32];
    __shared__ bf16_t Bs[128 * 32];
    const bool isbf = C32 ? detect_bf16(hs) : true;
    const int t = threadIdx.x;
    const int w = t >> 6, l = t & 63, l15 = l & 15, q = l >> 4;
    const int m0 = blockIdx.y * 128, n0 = blockIdx.x * 128;
    const int wm = (w >> 1) * 64, wn = (w & 1) * 64;
    floatx4 acc[4][4];
#pragma unroll
    for (int mi = 0; mi < 4; mi++)
#pragma unroll
        for (int ni = 0; ni < 4; ni++) acc[mi][ni] = floatx4{0.f, 0.f, 0.f, 0.f};

    const bf16_t* ga = A + (size_t)(m0 + (t >> 2)) * K + ((t & 3) << 3);
    const bf16_t* gb = Bt + (size_t)(n0 + (t >> 2)) * K + ((t & 3) << 3);
    bf16_t* lA = &As[(t >> 2) * 32 + ((t & 3) << 3)];
    bf16_t* lB = &Bs[(t >> 2) * 32 + ((t & 3) << 3)];

    for (int k0 = 0; k0 < K; k0 += 32) {
        __syncthreads();
        glld16(ga, lA);
        glld16(ga + (size_t)64 * K, lA + 64 * 32);
        glld16(gb, lB);
        glld16(gb + (size_t)64 * K, lB + 64 * 32);
        ga += 32; gb += 32;
        __syncthreads();
        bf16x8 af[4], bfr[4];
#pragma unroll
        for (int i = 0; i < 4; i++)
            af[i] = *(const bf16x8*)&As[(wm + i * 16 + l15) * 32 + q * 8];
#pragma unroll
        for (int i = 0; i < 4; i++)
            bfr[i] = *(const bf16x8*)&Bs[(wn + i * 16 + l15) * 32 + q * 8];
#pragma unroll
        for (int mi = 0; mi < 4; mi++)
#pragma unroll
            for (int ni = 0; ni < 4; ni++)
                acc[mi][ni] = MFMA16x16x32(af[mi], bfr[ni], acc[mi][ni]);
    }

    if (TV) {
        bf16_t* C = (bf16_t*)Cout;
#pragma unroll
        for (int mi = 0; mi < 4; mi++) {
            int s_base = m0 + wm + mi * 16 + q * 4;
#pragma unroll
            for (int ni = 0; ni < 4; ni++) {
                int e = n0 + wn + ni * 16 + l15;
                int h = e >> 8, dd = e & 255;
                bf16_t o4[4];
#pragma unroll
                for (int r = 0; r < 4; r++) o4[r] = (bf16_t)acc[mi][ni][r];
                *(uint2*)(C + (size_t)h * 524288 + (size_t)dd * 2048 + s_base) =
                    *(const uint2*)o4;
            }
        }
    } else if (C32 && !isbf) {
        float* C = (float*)Cout;
#pragma unroll
        for (int mi = 0; mi < 4; mi++)
#pragma unroll
            for (int ni = 0; ni < 4; ni++)
#pragma unroll
                for (int r = 0; r < 4; r++) {
                    int row = m0 + wm + mi * 16 + q * 4 + r;
                    int col = n0 + wn + ni * 16 + l15;
                    C[(size_t)row * 4096 + col] = acc[mi][ni][r];
                }
    } else {
        bf16_t* C = (bf16_t*)Cout;
#pragma unroll
        for (int mi = 0; mi < 4; mi++)
#pragma unroll
            for (int ni = 0; ni < 4; ni++)
#pragma unroll
                for (int r = 0; r < 4; r++) {
                    int row = m0 + wm + mi * 16 + q * 4 + r;
                    int col = n0 + wn + ni * 16 + l15;
                    C[(size_t)row * 4096 + col] = (bf16_t)acc[mi][ni][r];
                }
    }
}

// ---------------------------------------------------------------------------
// FALLBACK GEMM (round-4, proven): 512 threads, dbuf, register-A (fp32-able).
// ---------------------------------------------------------------------------
template <bool AHS, bool TV, bool CMAY32>
__global__ __launch_bounds__(512, 4) void gemm_nt(
    const void* __restrict__ Ain, const bf16_t* __restrict__ Bt,
    void* __restrict__ Cout, int n_off, const void* __restrict__ hs) {
    constexpr int K = 4096, NITER = K / 32;
    const bool isbf = (AHS || CMAY32) ? detect_bf16(hs) : true;
    __shared__ bf16_t As[2][128 * 32];
    __shared__ bf16_t Bs[2][128 * 32];
    const int t = threadIdx.x;
    const int w = t >> 6, l = t & 63, l15 = l & 15, q = l >> 4;
    const int m0 = blockIdx.y * 128, n0 = blockIdx.x * 128;
    const int wm = (w >> 2) * 64, wn = (w & 3) * 32;
    floatx4 acc[4][2];
#pragma unroll
    for (int mi = 0; mi < 4; mi++)
#pragma unroll
        for (int ni = 0; ni < 2; ni++) acc[mi][ni] = floatx4{0.f, 0.f, 0.f, 0.f};

    const int ar = t >> 2, ac = (t & 3) << 3;
    const bf16_t* Ab = (const bf16_t*)Ain;
    const float*  Af = (const float*)Ain;
    const bf16_t* gb = Bt + (size_t)(n0 + ar) * K + ac;
    const int lofs = ar * 32 + ac;

    bf16_t areg[8];
    float  freg[8];

    auto loadA = [&](int ki) {
        if (AHS && !isbf) {
            const float* s = Af + (size_t)(m0 + ar) * K + ki * 32 + ac;
            *(float4*)&freg[0] = *(const float4*)s;
            *(float4*)&freg[4] = *(const float4*)(s + 4);
        } else {
            *(uint4*)areg = *(const uint4*)(Ab + (size_t)(m0 + ar) * K + ki * 32 + ac);
        }
    };
    auto writeA = [&](int p) {
        if (AHS && !isbf) {
            bf16_t tmp[8];
#pragma unroll
            for (int j = 0; j < 8; j++) tmp[j] = (bf16_t)freg[j];
            *(uint4*)&As[p][lofs] = *(const uint4*)tmp;
        } else {
            *(uint4*)&As[p][lofs] = *(const uint4*)areg;
        }
    };

    loadA(0);
    writeA(0);
    glld16(gb, &Bs[0][lofs]);
    loadA(1);

    int p = 0;
    for (int i = 0; i < NITER; i++) {
        __syncthreads();
        if (i + 1 < NITER) {
            glld16(gb + (i + 1) * 32, &Bs[p ^ 1][lofs]);
            writeA(p ^ 1);
            if (i + 2 < NITER) loadA(i + 2);
        }
        bf16x8 af[4], bfr[2];
#pragma unroll
        for (int ii = 0; ii < 4; ii++)
            af[ii] = *(const bf16x8*)&As[p][(wm + ii * 16 + l15) * 32 + q * 8];
#pragma unroll
        for (int jj = 0; jj < 2; jj++)
            bfr[jj] = *(const bf16x8*)&Bs[p][(wn + jj * 16 + l15) * 32 + q * 8];
#pragma unroll
        for (int mi = 0; mi < 4; mi++)
#pragma unroll
            for (int ni = 0; ni < 2; ni++)
                acc[mi][ni] = MFMA16x16x32(af[mi], bfr[ni], acc[mi][ni]);
        p ^= 1;
    }

    if (TV) {
        bf16_t* C = (bf16_t*)Cout;
#pragma unroll
        for (int mi = 0; mi < 4; mi++) {
            int s_base = m0 + wm + mi * 16 + q * 4;
#pragma unroll
            for (int ni = 0; ni < 2; ni++) {
                int e = n_off + n0 + wn + ni * 16 + l15;
                int h = e >> 8, dd = e & 255;
                bf16_t o4[4];
#pragma unroll
                for (int r = 0; r < 4; r++) o4[r] = (bf16_t)acc[mi][ni][r];
                *(uint2*)(C + (size_t)h * 524288 + (size_t)dd * 2048 + s_base) =
                    *(const uint2*)o4;
            }
        }
    } else if (CMAY32 && !isbf) {
        float* C = (float*)Cout;
#pragma unroll
        for (int mi = 0; mi < 4; mi++)
#pragma unroll
            for (int ni = 0; ni < 2; ni++)
#pragma unroll
                for (int r = 0; r < 4; r++) {
                    int row = m0 + wm + mi * 16 + q * 4 + r;
                    int col = n_off + n0 + wn + ni * 16 + l15;
                    C[(size_t)row * 4096 + col] = acc[mi][ni][r];
                }
    } else {
        bf16_t* C = (bf16_t*)Cout;
#pragma unroll
        for (int mi = 0; mi < 4; mi++)
#pragma unroll
            for (int ni = 0; ni < 2; ni++)
#pragma unroll
                for (int r = 0; r < 4; r++) {
                    int row = m0 + wm + mi * 16 + q * 4 + r;
                    int col = n_off + n0 + wn + ni * 16 + l15;
                    C[(size_t)row * 4096 + col] = (bf16_t)acc[mi][ni][r];
                }
    }
}

// ---------------------------------------------------------------------------
// GPT-J interleaved RoPE on first 64 dims of each 256-dim head, Q and K.
// ---------------------------------------------------------------------------
__global__ __launch_bounds__(256) void rope_qk(
    bf16_t* __restrict__ Q, bf16_t* __restrict__ K,
    const int* __restrict__ pos_ids) {
    int tid = blockIdx.x * 256 + threadIdx.x;
    int i = tid & 31;
    int h = (tid >> 5) & 15;
    int s = tid >> 9;
    float p = (float)pos_ids[s];
    float inv = __expf(-(float)i * 0.28782313662425572f);  // 10000^(-i/32)
    float ang = p * inv;
    float sn, cs;
    __sincosf(ang, &sn, &cs);
    size_t base = (size_t)s * 4096 + h * 256 + 2 * i;
    float q0 = (float)Q[base], q1 = (float)Q[base + 1];
    Q[base]     = (bf16_t)(q0 * cs - q1 * sn);
    Q[base + 1] = (bf16_t)(q1 * cs + q0 * sn);
    float k0 = (float)K[base], k1 = (float)K[base + 1];
    K[base]     = (bf16_t)(k0 * cs - k1 * sn);
    K[base + 1] = (bf16_t)(k1 * cs + k0 * sn);
}

// ---------------------------------------------------------------------------
// Flash attention, CAUSAL-BALANCED (deterministic: block bx does q-tiles
// {bx, 31-bx} sequentially = exactly 66 k-tiles; placement-independent).
// v5 = round-3 structure with the REAL fix: round-3 put a __syncthreads()
// (which always drains vmcnt(0)) right after the prefetch loads, so the
// pipeline hid nothing. The barrier after {WRITET; LOADT(next)} is now a
// raw s_barrier + lgkmcnt(0) only (barrier_keep_vmcnt): ds-writes become
// visible, but the 8 prefetch loads stay in flight across the barrier and
// complete under compute(). The top-of-iteration __syncthreads() keeps its
// vmcnt(0) drain -- by then the loads have had a full compute phase, so the
// drain is ~free, and LDS overwrite ordering stays trivially safe.
// Register dbuf remains statically-named uint4 scalars (rule #20).
// ---------------------------------------------------------------------------
__global__ __launch_bounds__(256, 1) void attn_kernel(
    const bf16_t* __restrict__ Q, const bf16_t* __restrict__ K,
    const bf16_t* __restrict__ Vt, bf16_t* __restrict__ Ctx) {
    __shared__ bf16_t Ks[32 * 264];
    __shared__ bf16_t Vs[256 * 40];
    __shared__ bf16_t Ps[4 * 16 * 40];
    const int h = blockIdx.y;
    const int t = threadIdx.x, w = t >> 6, l = t & 63, l15 = l & 15, q = l >> 4;

    // fixed per-thread staging coordinates (identical layout to round-0)
    const int kd16  = (t & 31) << 3;   // K: col offset in head-dim
    const int kkey0 = t >> 5;          // K: base row 0..7 (rows kkey0+{0,8,16,24})
    const int vk8   = (t & 3) << 3;    // V: key-col offset
    const int vd0   = t >> 2;          // V: base d 0..63 (d = vd0+{0,64,128,192})

    const bf16_t* Kbase = K + (size_t)kkey0 * 4096 + h * 256 + kd16;
    const bf16_t* Vbase = Vt + (size_t)h * 524288 + (size_t)vd0 * 2048 + vk8;

    uint4 ka0, ka1, ka2, ka3, va0, va1, va2, va3;
    uint4 kb0, kb1, kb2, kb3, vb0, vb1, vb2, vb3;

#define LOADT(kt, k0, k1, k2, k3, v0, v1, v2, v3)                              \
    do {                                                                       \
        const bf16_t* kp_ = Kbase + (size_t)(kt) * (32 * 4096);                \
        k0 = *(const uint4*)(kp_);                                             \
        k1 = *(const uint4*)(kp_ + (size_t)8 * 4096);                          \
        k2 = *(const uint4*)(kp_ + (size_t)16 * 4096);                         \
        k3 = *(const uint4*)(kp_ + (size_t)24 * 4096);                         \
        const bf16_t* vp_ = Vbase + (kt) * 32;                                 \
        v0 = *(const uint4*)(vp_);                                             \
        v1 = *(const uint4*)(vp_ + (size_t)64 * 2048);                         \
        v2 = *(const uint4*)(vp_ + (size_t)128 * 2048);                        \
        v3 = *(const uint4*)(vp_ + (size_t)192 * 2048);                        \
    } while (0)

#define WRITET(k0, k1, k2, k3, v0, v1, v2, v3)                                 \
    do {                                                                       \
        *(uint4*)&Ks[kkey0 * 264 + kd16]        = k0;                          \
        *(uint4*)&Ks[(8 + kkey0) * 264 + kd16]  = k1;                          \
        *(uint4*)&Ks[(16 + kkey0) * 264 + kd16] = k2;                          \
        *(uint4*)&Ks[(24 + kkey0) * 264 + kd16] = k3;                          \
        *(uint4*)&Vs[vd0 * 40 + vk8]            = v0;                          \
        *(uint4*)&Vs[(64 + vd0) * 40 + vk8]     = v1;                          \
        *(uint4*)&Vs[(128 + vd0) * 40 + vk8]    = v2;                          \
        *(uint4*)&Vs[(192 + vd0) * 40 + vk8]    = v3;                          \
    } while (0)

    LOADT(0, ka0, ka1, ka2, ka3, va0, va1, va2, va3);  // prime (pass 0, kt 0)

    for (int pass = 0; pass < 2; pass++) {
        const int qt = pass ? (31 - (int)blockIdx.x) : (int)blockIdx.x;
        const int qr = qt * 64 + w * 16;

        bf16x8 qf[8];
        {
            const bf16_t* qp = Q + (size_t)(qr + l15) * 4096 + h * 256 + q * 8;
#pragma unroll
            for (int tt = 0; tt < 8; tt++) qf[tt] = *(const bf16x8*)(qp + tt * 32);
        }
        floatx4 O[16];
#pragma unroll
        for (int i = 0; i < 16; i++) O[i] = floatx4{0.f, 0.f, 0.f, 0.f};
        float mrow[4] = {-1e30f, -1e30f, -1e30f, -1e30f};
        float lrow[4] = {0.f, 0.f, 0.f, 0.f};

        auto compute = [&](int kt) {
            floatx4 sc0 = floatx4{0.f, 0.f, 0.f, 0.f};
            floatx4 sc1 = floatx4{0.f, 0.f, 0.f, 0.f};
#pragma unroll
            for (int tt = 0; tt < 8; tt++) {
                bf16x8 k0f = *(const bf16x8*)&Ks[l15 * 264 + tt * 32 + q * 8];
                bf16x8 k1f = *(const bf16x8*)&Ks[(16 + l15) * 264 + tt * 32 + q * 8];
                sc0 = MFMA16x16x32(qf[tt], k0f, sc0);
                sc1 = MFMA16x16x32(qf[tt], k1f, sc1);
            }
            const bool diag = (kt >= 2 * qt);
#pragma unroll
            for (int r = 0; r < 4; r++) {
                int grow = qr + q * 4 + r;
                float v0 = sc0[r] * 0.0625f;
                float v1 = sc1[r] * 0.0625f;
                if (diag) {
                    if (kt * 32 + l15 > grow) v0 = -1e30f;
                    if (kt * 32 + 16 + l15 > grow) v1 = -1e30f;
                }
                float mx = fmaxf(v0, v1);
#pragma unroll
                for (int d = 1; d < 16; d <<= 1) mx = fmaxf(mx, __shfl_xor(mx, d, 64));
                if (mx > mrow[r]) {  // bit-exact skip: alpha==1 otherwise
                    float alpha = __expf(mrow[r] - mx);
                    lrow[r] *= alpha;
#pragma unroll
                    for (int ni = 0; ni < 16; ni++) O[ni][r] *= alpha;
                    mrow[r] = mx;
                }
                float p0 = __expf(v0 - mrow[r]), p1 = __expf(v1 - mrow[r]);
                float rsum = p0 + p1;
#pragma unroll
                for (int d = 1; d < 16; d <<= 1) rsum += __shfl_xor(rsum, d, 64);
                lrow[r] += rsum;
                Ps[w * 640 + (q * 4 + r) * 40 + l15] = (bf16_t)p0;
                Ps[w * 640 + (q * 4 + r) * 40 + 16 + l15] = (bf16_t)p1;
            }
            bf16x8 pf = *(const bf16x8*)&Ps[w * 640 + l15 * 40 + q * 8];
#pragma unroll
            for (int ni = 0; ni < 16; ni++) {
                bf16x8 vf = *(const bf16x8*)&Vs[(ni * 16 + l15) * 40 + q * 8];
                O[ni] = MFMA16x16x32(pf, vf, O[ni]);
            }
        };

        const int nkt = 2 * qt + 2;  // always even
        for (int kt = 0; kt < nkt; kt += 2) {
            // ---- even iteration: A-regs hold tile kt ----
            __syncthreads();                                   // full drain: prev
                                                               // loads ~complete
            WRITET(ka0, ka1, ka2, ka3, va0, va1, va2, va3);
            LOADT(kt + 1, kb0, kb1, kb2, kb3, vb0, vb1, vb2, vb3);
            barrier_keep_vmcnt();                              // B loads stay in flight
            compute(kt);
            // ---- odd iteration: B-regs hold tile kt+1 ----
            __syncthreads();
            WRITET(kb0, kb1, kb2, kb3, vb0, vb1, vb2, vb3);
            if (kt + 2 < nkt) {
                LOADT(kt + 2, ka0, ka1, ka2, ka3, va0, va1, va2, va3);
            } else if (pass == 0) {
                LOADT(0, ka0, ka1, ka2, ka3, va0, va1, va2, va3);  // pass-1 kt0
            }
            barrier_keep_vmcnt();                              // A loads stay in flight
            compute(kt + 1);
        }

#pragma unroll
        for (int ni = 0; ni < 16; ni++)
#pragma unroll
            for (int r = 0; r < 4; r++) {
                int grow = qr + q * 4 + r;
                Ctx[(size_t)grow * 4096 + h * 256 + ni * 16 + l15] =
                    (bf16_t)(O[ni][r] / lrow[r]);
            }
    }
#undef LOADT
#undef WRITET
}

// ---------------------------------------------------------------------------
// FAST path (ws >= 80MB):  A0=[0,16M) Hb->Ctx | A1=[16,48M) Wt | A2=[48,64M) K
//                          | A3=[64,80M) Vt | Q in d_out.
// FALLBACK (48MB, round-4 proven): R0 Wt/Ctx | R1 Vt | R2 K | Q in d_out.
// Branch on ws_size: constant every call -> graph-safe.
// ---------------------------------------------------------------------------
extern "C" void kernel_launch(void* const* d_in, const int* in_sizes, int n_in,
                              void* d_out, int out_size, void* d_ws, size_t ws_size,
                              hipStream_t stream) {
    const void* hs = d_in[0];
    const void* wq = d_in[1];
    const void* wk = d_in[2];
    const void* wv = d_in[3];
    const void* wo = d_in[4];
    const int* pos = (const int*)d_in[5];

    char* ws = (char*)d_ws;
    dim3 tT(256), tb(256);
    dim3 gTfull(64, 64);
    bf16_t* Qb = (bf16_t*)d_out;

    if (ws_size >= ((size_t)80 << 20)) {
        // ---------------- fast path: m97 GEMMs on bf16 hs ----------------
        bf16_t* Hb  = (bf16_t*)ws;                          // -> Ctx later
        bf16_t* Wt  = (bf16_t*)(ws + ((size_t)16 << 20));
        bf16_t* Kb  = (bf16_t*)(ws + ((size_t)48 << 20));
        bf16_t* Vt  = (bf16_t*)(ws + ((size_t)64 << 20));
        bf16_t* Ctx = Hb;
        dim3 gG(32, 16);

        conv_hs<<<dim3(4096), tb, 0, stream>>>(hs, Hb);

        transpose_w<<<gTfull, tT, 0, stream>>>(wq, Wt, 0, hs);
        gemm_bf16a<false, false><<<gG, tb, 0, stream>>>(Hb, Wt, Qb, hs);
        transpose_w<<<gTfull, tT, 0, stream>>>(wk, Wt, 0, hs);
        gemm_bf16a<false, false><<<gG, tb, 0, stream>>>(Hb, Wt, Kb, hs);
        transpose_w<<<gTfull, tT, 0, stream>>>(wv, Wt, 0, hs);
        gemm_bf16a<true, false><<<gG, tb, 0, stream>>>(Hb, Wt, Vt, hs);

        rope_qk<<<dim3(4096), tb, 0, stream>>>(Qb, Kb, pos);

        attn_kernel<<<dim3(16, 16), tb, 0, stream>>>(Qb, Kb, Vt, Ctx);  // Hb dead

        transpose_w<<<gTfull, tT, 0, stream>>>(wo, Wt, 0, hs);
        gemm_bf16a<false, true><<<gG, tb, 0, stream>>>(Ctx, Wt, d_out, hs);  // Q dead
    } else {
        // ---------------- fallback: round-4 proven 48 MB pipeline --------
        bf16_t* R0 = (bf16_t*)ws;
        bf16_t* R1 = (bf16_t*)(ws + ((size_t)16 << 20));
        bf16_t* R2 = (bf16_t*)(ws + ((size_t)32 << 20));
        bf16_t* Kb  = R2;
        bf16_t* Vt  = R1;
        bf16_t* Ctx = R0;
        dim3 tG(512);
        dim3 gThalf(64, 32);
        dim3 gGfull(32, 16), gGhalf(16, 16);

        transpose_w<<<gTfull, tT, 0, stream>>>(wq, R0, 0, hs);
        gemm_nt<true, false, false><<<gGfull, tG, 0, stream>>>(hs, R0, Qb, 0, hs);
        transpose_w<<<gTfull, tT, 0, stream>>>(wk, R0, 0, hs);
        gemm_nt<true, false, false><<<gGfull, tG, 0, stream>>>(hs, R0, Kb, 0, hs);
        transpose_w<<<gThalf, tT, 0, stream>>>(wv, R0, 0, hs);
        gemm_nt<true, true, false><<<gGhalf, tG, 0, stream>>>(hs, R0, Vt, 0, hs);
        transpose_w<<<gThalf, tT, 0, stream>>>(wv, R0, 2048, hs);
        gemm_nt<true, true, false><<<gGhalf, tG, 0, stream>>>(hs, R0, Vt, 2048, hs);

        rope_qk<<<dim3(4096), tb, 0, stream>>>(Qb, Kb, pos);

        attn_kernel<<<dim3(16, 16), tb, 0, stream>>>(Qb, Kb, Vt, Ctx);

        transpose_w<<<gThalf, tT, 0, stream>>>(wo, R2, 0, hs);
        gemm_nt<false, false, true><<<gGhalf, tG, 0, stream>>>(Ctx, R2, d_out, 0, hs);
        transpose_w<<<gThalf, tT, 0, stream>>>(wo, R2, 2048, hs);
        gemm_nt<false, false, true><<<gGhalf, tG, 0, stream>>>(Ctx, R2, d_out, 2048, hs);
    }
}

// Round 5
// 769.396 us; speedup vs baseline: 1.0684x; 1.0684x over previous
//
#include <hip/hip_runtime.h>
#include <hip/hip_bf16.h>

typedef __bf16 bf16_t;
typedef __attribute__((ext_vector_type(8))) __bf16 bf16x8;
typedef __attribute__((ext_vector_type(4))) float floatx4;

#define MFMA16x16x32(a, b, c) __builtin_amdgcn_mfma_f32_16x16x32_bf16((a), (b), (c), 0, 0, 0)

__device__ __forceinline__ void glld16(const bf16_t* g, bf16_t* l) {
    __builtin_amdgcn_global_load_lds(
        (const __attribute__((address_space(1))) unsigned int*)g,
        (__attribute__((address_space(3))) unsigned int*)l,
        16, 0, 0);
}

// ---------------------------------------------------------------------------
// On-device dtype sniffer (proven): bf16-pair u32 bits 14..7 are the low
// element's exponent, in [112,142] for N(0,1)-ish data; fp32 -> uniform.
// ---------------------------------------------------------------------------
__device__ __forceinline__ bool detect_bf16(const void* hs) {
    const unsigned* u = (const unsigned*)hs;
    int c = 0;
#pragma unroll 8
    for (int i = 0; i < 64; i++) {
        unsigned e = (u[i] >> 7) & 0xFFu;
        c += (e >= 112u && e <= 142u) ? 1 : 0;
    }
    return c >= 32;
}

// ---------------------------------------------------------------------------
// hs -> bf16 copy/convert (fast path). 8 elems/thread.
// ---------------------------------------------------------------------------
__global__ __launch_bounds__(256) void conv_hs(
    const void* __restrict__ src, bf16_t* __restrict__ dst) {
    const bool isbf = detect_bf16(src);
    size_t i8 = ((size_t)blockIdx.x * 256 + threadIdx.x) * 8;
    if (isbf) {
        *(uint4*)(dst + i8) = *(const uint4*)((const bf16_t*)src + i8);
    } else {
        const float* s = (const float*)src + i8;
        float4 f0 = *(const float4*)s;
        float4 f1 = *(const float4*)(s + 4);
        bf16_t tmp[8];
        tmp[0] = (bf16_t)f0.x; tmp[1] = (bf16_t)f0.y;
        tmp[2] = (bf16_t)f0.z; tmp[3] = (bf16_t)f0.w;
        tmp[4] = (bf16_t)f1.x; tmp[5] = (bf16_t)f1.y;
        tmp[6] = (bf16_t)f1.z; tmp[7] = (bf16_t)f1.w;
        *(uint4*)(dst + i8) = *(const uint4*)tmp;
    }
}

// ---------------------------------------------------------------------------
// 64x64-tiled transpose of W cols [coff, coff+64*gridDim.y) into bf16
// Wt[c][r] (dst row-stride 4096). Source dtype sniffed from hs.
// ---------------------------------------------------------------------------
__global__ __launch_bounds__(256) void transpose_w(
    const void* __restrict__ src, bf16_t* __restrict__ dst,
    int coff, const void* __restrict__ hs) {
    const bool isbf = detect_bf16(hs);
    __shared__ bf16_t T[64 * 68];
    const int r0 = blockIdx.x * 64, c0 = blockIdx.y * 64;
    const int t = threadIdx.x;
#pragma unroll
    for (int i = 0; i < 2; i++) {
        int idx = i * 256 + t;
        int r = idx >> 3, c8 = (idx & 7) << 3;
        bf16_t tmp[8];
        if (isbf) {
            *(uint4*)tmp = *(const uint4*)((const bf16_t*)src +
                              (size_t)(r0 + r) * 4096 + coff + c0 + c8);
        } else {
            const float* s = (const float*)src + (size_t)(r0 + r) * 4096 + coff + c0 + c8;
            float4 f0 = *(const float4*)s;
            float4 f1 = *(const float4*)(s + 4);
            tmp[0] = (bf16_t)f0.x; tmp[1] = (bf16_t)f0.y;
            tmp[2] = (bf16_t)f0.z; tmp[3] = (bf16_t)f0.w;
            tmp[4] = (bf16_t)f1.x; tmp[5] = (bf16_t)f1.y;
            tmp[6] = (bf16_t)f1.z; tmp[7] = (bf16_t)f1.w;
        }
        *(uint2*)&T[r * 68 + c8]     = *(const uint2*)&tmp[0];
        *(uint2*)&T[r * 68 + c8 + 4] = *(const uint2*)&tmp[4];
    }
    __syncthreads();
#pragma unroll
    for (int i = 0; i < 2; i++) {
        int idx = i * 256 + t;
        int c = idx >> 3, r8 = (idx & 7) << 3;
        bf16_t tmp[8];
#pragma unroll
        for (int j = 0; j < 8; j++) tmp[j] = T[(r8 + j) * 68 + c];
        *(uint4*)(dst + (size_t)(c0 + c) * 4096 + r0 + r8) = *(const uint4*)tmp;
    }
}

// ---------------------------------------------------------------------------
// FAST-PATH GEMM (m97 structure, bf16 A): C[2048,4096] = A @ Bt^T.
// ---------------------------------------------------------------------------
template <bool TV, bool C32>
__global__ __launch_bounds__(256, 2) void gemm_bf16a(
    const bf16_t* __restrict__ A, const bf16_t* __restrict__ Bt,
    void* __restrict__ Cout, const void* __restrict__ hs) {
    constexpr int K = 4096;
    __shared__ bf16_t As[128 * 32];
    __shared__ bf16_t Bs[128 * 32];
    const bool isbf = C32 ? detect_bf16(hs) : true;
    const int t = threadIdx.x;
    const int w = t >> 6, l = t & 63, l15 = l & 15, q = l >> 4;
    const int m0 = blockIdx.y * 128, n0 = blockIdx.x * 128;
    const int wm = (w >> 1) * 64, wn = (w & 1) * 64;
    floatx4 acc[4][4];
#pragma unroll
    for (int mi = 0; mi < 4; mi++)
#pragma unroll
        for (int ni = 0; ni < 4; ni++) acc[mi][ni] = floatx4{0.f, 0.f, 0.f, 0.f};

    const bf16_t* ga = A + (size_t)(m0 + (t >> 2)) * K + ((t & 3) << 3);
    const bf16_t* gb = Bt + (size_t)(n0 + (t >> 2)) * K + ((t & 3) << 3);
    bf16_t* lA = &As[(t >> 2) * 32 + ((t & 3) << 3)];
    bf16_t* lB = &Bs[(t >> 2) * 32 + ((t & 3) << 3)];

    for (int k0 = 0; k0 < K; k0 += 32) {
        __syncthreads();
        glld16(ga, lA);
        glld16(ga + (size_t)64 * K, lA + 64 * 32);
        glld16(gb, lB);
        glld16(gb + (size_t)64 * K, lB + 64 * 32);
        ga += 32; gb += 32;
        __syncthreads();
        bf16x8 af[4], bfr[4];
#pragma unroll
        for (int i = 0; i < 4; i++)
            af[i] = *(const bf16x8*)&As[(wm + i * 16 + l15) * 32 + q * 8];
#pragma unroll
        for (int i = 0; i < 4; i++)
            bfr[i] = *(const bf16x8*)&Bs[(wn + i * 16 + l15) * 32 + q * 8];
#pragma unroll
        for (int mi = 0; mi < 4; mi++)
#pragma unroll
            for (int ni = 0; ni < 4; ni++)
                acc[mi][ni] = MFMA16x16x32(af[mi], bfr[ni], acc[mi][ni]);
    }

    if (TV) {
        bf16_t* C = (bf16_t*)Cout;
#pragma unroll
        for (int mi = 0; mi < 4; mi++) {
            int s_base = m0 + wm + mi * 16 + q * 4;
#pragma unroll
            for (int ni = 0; ni < 4; ni++) {
                int e = n0 + wn + ni * 16 + l15;
                int h = e >> 8, dd = e & 255;
                bf16_t o4[4];
#pragma unroll
                for (int r = 0; r < 4; r++) o4[r] = (bf16_t)acc[mi][ni][r];
                *(uint2*)(C + (size_t)h * 524288 + (size_t)dd * 2048 + s_base) =
                    *(const uint2*)o4;
            }
        }
    } else if (C32 && !isbf) {
        float* C = (float*)Cout;
#pragma unroll
        for (int mi = 0; mi < 4; mi++)
#pragma unroll
            for (int ni = 0; ni < 4; ni++)
#pragma unroll
                for (int r = 0; r < 4; r++) {
                    int row = m0 + wm + mi * 16 + q * 4 + r;
                    int col = n0 + wn + ni * 16 + l15;
                    C[(size_t)row * 4096 + col] = acc[mi][ni][r];
                }
    } else {
        bf16_t* C = (bf16_t*)Cout;
#pragma unroll
        for (int mi = 0; mi < 4; mi++)
#pragma unroll
            for (int ni = 0; ni < 4; ni++)
#pragma unroll
                for (int r = 0; r < 4; r++) {
                    int row = m0 + wm + mi * 16 + q * 4 + r;
                    int col = n0 + wn + ni * 16 + l15;
                    C[(size_t)row * 4096 + col] = (bf16_t)acc[mi][ni][r];
                }
    }
}

// ---------------------------------------------------------------------------
// FALLBACK GEMM (proven): 512 threads, dbuf, register-A (fp32-able).
// ---------------------------------------------------------------------------
template <bool AHS, bool TV, bool CMAY32>
__global__ __launch_bounds__(512, 4) void gemm_nt(
    const void* __restrict__ Ain, const bf16_t* __restrict__ Bt,
    void* __restrict__ Cout, int n_off, const void* __restrict__ hs) {
    constexpr int K = 4096, NITER = K / 32;
    const bool isbf = (AHS || CMAY32) ? detect_bf16(hs) : true;
    __shared__ bf16_t As[2][128 * 32];
    __shared__ bf16_t Bs[2][128 * 32];
    const int t = threadIdx.x;
    const int w = t >> 6, l = t & 63, l15 = l & 15, q = l >> 4;
    const int m0 = blockIdx.y * 128, n0 = blockIdx.x * 128;
    const int wm = (w >> 2) * 64, wn = (w & 3) * 32;
    floatx4 acc[4][2];
#pragma unroll
    for (int mi = 0; mi < 4; mi++)
#pragma unroll
        for (int ni = 0; ni < 2; ni++) acc[mi][ni] = floatx4{0.f, 0.f, 0.f, 0.f};

    const int ar = t >> 2, ac = (t & 3) << 3;
    const bf16_t* Ab = (const bf16_t*)Ain;
    const float*  Af = (const float*)Ain;
    const bf16_t* gb = Bt + (size_t)(n0 + ar) * K + ac;
    const int lofs = ar * 32 + ac;

    bf16_t areg[8];
    float  freg[8];

    auto loadA = [&](int ki) {
        if (AHS && !isbf) {
            const float* s = Af + (size_t)(m0 + ar) * K + ki * 32 + ac;
            *(float4*)&freg[0] = *(const float4*)s;
            *(float4*)&freg[4] = *(const float4*)(s + 4);
        } else {
            *(uint4*)areg = *(const uint4*)(Ab + (size_t)(m0 + ar) * K + ki * 32 + ac);
        }
    };
    auto writeA = [&](int p) {
        if (AHS && !isbf) {
            bf16_t tmp[8];
#pragma unroll
            for (int j = 0; j < 8; j++) tmp[j] = (bf16_t)freg[j];
            *(uint4*)&As[p][lofs] = *(const uint4*)tmp;
        } else {
            *(uint4*)&As[p][lofs] = *(const uint4*)areg;
        }
    };

    loadA(0);
    writeA(0);
    glld16(gb, &Bs[0][lofs]);
    loadA(1);

    int p = 0;
    for (int i = 0; i < NITER; i++) {
        __syncthreads();
        if (i + 1 < NITER) {
            glld16(gb + (i + 1) * 32, &Bs[p ^ 1][lofs]);
            writeA(p ^ 1);
            if (i + 2 < NITER) loadA(i + 2);
        }
        bf16x8 af[4], bfr[2];
#pragma unroll
        for (int ii = 0; ii < 4; ii++)
            af[ii] = *(const bf16x8*)&As[p][(wm + ii * 16 + l15) * 32 + q * 8];
#pragma unroll
        for (int jj = 0; jj < 2; jj++)
            bfr[jj] = *(const bf16x8*)&Bs[p][(wn + jj * 16 + l15) * 32 + q * 8];
#pragma unroll
        for (int mi = 0; mi < 4; mi++)
#pragma unroll
            for (int ni = 0; ni < 2; ni++)
                acc[mi][ni] = MFMA16x16x32(af[mi], bfr[ni], acc[mi][ni]);
        p ^= 1;
    }

    if (TV) {
        bf16_t* C = (bf16_t*)Cout;
#pragma unroll
        for (int mi = 0; mi < 4; mi++) {
            int s_base = m0 + wm + mi * 16 + q * 4;
#pragma unroll
            for (int ni = 0; ni < 2; ni++) {
                int e = n_off + n0 + wn + ni * 16 + l15;
                int h = e >> 8, dd = e & 255;
                bf16_t o4[4];
#pragma unroll
                for (int r = 0; r < 4; r++) o4[r] = (bf16_t)acc[mi][ni][r];
                *(uint2*)(C + (size_t)h * 524288 + (size_t)dd * 2048 + s_base) =
                    *(const uint2*)o4;
            }
        }
    } else if (CMAY32 && !isbf) {
        float* C = (float*)Cout;
#pragma unroll
        for (int mi = 0; mi < 4; mi++)
#pragma unroll
            for (int ni = 0; ni < 2; ni++)
#pragma unroll
                for (int r = 0; r < 4; r++) {
                    int row = m0 + wm + mi * 16 + q * 4 + r;
                    int col = n_off + n0 + wn + ni * 16 + l15;
                    C[(size_t)row * 4096 + col] = acc[mi][ni][r];
                }
    } else {
        bf16_t* C = (bf16_t*)Cout;
#pragma unroll
        for (int mi = 0; mi < 4; mi++)
#pragma unroll
            for (int ni = 0; ni < 2; ni++)
#pragma unroll
                for (int r = 0; r < 4; r++) {
                    int row = m0 + wm + mi * 16 + q * 4 + r;
                    int col = n_off + n0 + wn + ni * 16 + l15;
                    C[(size_t)row * 4096 + col] = (bf16_t)acc[mi][ni][r];
                }
    }
}

// ---------------------------------------------------------------------------
// GPT-J interleaved RoPE on first 64 dims of each 256-dim head, Q and K.
// ---------------------------------------------------------------------------
__global__ __launch_bounds__(256) void rope_qk(
    bf16_t* __restrict__ Q, bf16_t* __restrict__ K,
    const int* __restrict__ pos_ids) {
    int tid = blockIdx.x * 256 + threadIdx.x;
    int i = tid & 31;
    int h = (tid >> 5) & 15;
    int s = tid >> 9;
    float p = (float)pos_ids[s];
    float inv = __expf(-(float)i * 0.28782313662425572f);  // 10000^(-i/32)
    float ang = p * inv;
    float sn, cs;
    __sincosf(ang, &sn, &cs);
    size_t base = (size_t)s * 4096 + h * 256 + 2 * i;
    float q0 = (float)Q[base], q1 = (float)Q[base + 1];
    Q[base]     = (bf16_t)(q0 * cs - q1 * sn);
    Q[base + 1] = (bf16_t)(q1 * cs + q0 * sn);
    float k0 = (float)K[base], k1 = (float)K[base + 1];
    K[base]     = (bf16_t)(k0 * cs - k1 * sn);
    K[base + 1] = (bf16_t)(k1 * cs + k0 * sn);
}

// ---------------------------------------------------------------------------
// Flash attention SPLIT-K (fast path): block (bx, h, half) does HALF the
// k-range of q-tile bx AND half of q-tile 31-bx = (bx+1)+(32-bx) = exactly
// 33 k-tiles for EVERY block. Grid (16,16,2) = 512 uniform-cost blocks ->
// 2 resident blocks/CU (LDS 2x42.5KB) regardless of dispatch placement:
// cross-block TLP hides the serial chain that 1-block/CU could not
// (round-1 measured 1.51x per-unit speedup at 2 blocks/CU; its loss was
// imbalance, which uniform cost eliminates). Partials: normalized ctx
// (bf16) + per-row (m,l) fp32; merged by merge_ctx. Fully-masked rows
// (qt=0,half=1,rows 0..31) leave m=-1e30 -> merge weight underflows to 0.
// Body = round-0 proven simple staging (124 VGPR), gated rescale
// (bit-exact: alpha==1 when skipped).
// ---------------------------------------------------------------------------
__global__ __launch_bounds__(256, 2) void attn_split(
    const bf16_t* __restrict__ Q, const bf16_t* __restrict__ K,
    const bf16_t* __restrict__ Vt, bf16_t* __restrict__ C0,
    bf16_t* __restrict__ C1, float2* __restrict__ Ml) {
    __shared__ bf16_t Ks[32 * 264];
    __shared__ bf16_t Vs[256 * 40];
    __shared__ bf16_t Ps[4 * 16 * 40];
    const int h = blockIdx.y;
    const int half = blockIdx.z;
    const int t = threadIdx.x, w = t >> 6, l = t & 63, l15 = l & 15, q = l >> 4;
    bf16_t* __restrict__ Cp = half ? C1 : C0;
    float2* __restrict__ mlp = Ml + (size_t)half * (2048 * 16);

    for (int seg = 0; seg < 2; seg++) {
        const int qt = seg ? (31 - (int)blockIdx.x) : (int)blockIdx.x;
        const int qr = qt * 64 + w * 16;
        const int nt2 = qt + 1;                 // tiles in this half
        const int ktbeg = half * nt2, ktend = ktbeg + nt2;

        bf16x8 qf[8];
        {
            const bf16_t* qp = Q + (size_t)(qr + l15) * 4096 + h * 256 + q * 8;
#pragma unroll
            for (int tt = 0; tt < 8; tt++) qf[tt] = *(const bf16x8*)(qp + tt * 32);
        }
        floatx4 O[16];
#pragma unroll
        for (int i = 0; i < 16; i++) O[i] = floatx4{0.f, 0.f, 0.f, 0.f};
        float mrow[4] = {-1e30f, -1e30f, -1e30f, -1e30f};
        float lrow[4] = {0.f, 0.f, 0.f, 0.f};

        for (int kt = ktbeg; kt < ktend; kt++) {
            __syncthreads();
#pragma unroll
            for (int i = 0; i < 4; i++) {
                int idx = i * 256 + t;
                int key = idx >> 5, d16 = (idx & 31) << 3;
                uint4 v = *(const uint4*)(K + (size_t)(kt * 32 + key) * 4096 + h * 256 + d16);
                *(uint4*)&Ks[key * 264 + d16] = v;
            }
#pragma unroll
            for (int i = 0; i < 4; i++) {
                int idx = i * 256 + t;
                int d = idx >> 2, k8 = (idx & 3) << 3;
                uint4 v = *(const uint4*)(Vt + (size_t)h * 524288 + (size_t)d * 2048 + kt * 32 + k8);
                *(uint4*)&Vs[d * 40 + k8] = v;
            }
            __syncthreads();

            floatx4 sc0 = floatx4{0.f, 0.f, 0.f, 0.f};
            floatx4 sc1 = floatx4{0.f, 0.f, 0.f, 0.f};
#pragma unroll
            for (int tt = 0; tt < 8; tt++) {
                bf16x8 k0f = *(const bf16x8*)&Ks[l15 * 264 + tt * 32 + q * 8];
                bf16x8 k1f = *(const bf16x8*)&Ks[(16 + l15) * 264 + tt * 32 + q * 8];
                sc0 = MFMA16x16x32(qf[tt], k0f, sc0);
                sc1 = MFMA16x16x32(qf[tt], k1f, sc1);
            }

            const bool diag = (kt >= 2 * qt);
#pragma unroll
            for (int r = 0; r < 4; r++) {
                int grow = qr + q * 4 + r;
                float v0 = sc0[r] * 0.0625f;
                float v1 = sc1[r] * 0.0625f;
                if (diag) {
                    if (kt * 32 + l15 > grow) v0 = -1e30f;
                    if (kt * 32 + 16 + l15 > grow) v1 = -1e30f;
                }
                float mx = fmaxf(v0, v1);
#pragma unroll
                for (int d = 1; d < 16; d <<= 1) mx = fmaxf(mx, __shfl_xor(mx, d, 64));
                if (mx > mrow[r]) {  // bit-exact skip: alpha==1 otherwise
                    float alpha = __expf(mrow[r] - mx);
                    lrow[r] *= alpha;
#pragma unroll
                    for (int ni = 0; ni < 16; ni++) O[ni][r] *= alpha;
                    mrow[r] = mx;
                }
                float p0 = __expf(v0 - mrow[r]), p1 = __expf(v1 - mrow[r]);
                float rsum = p0 + p1;
#pragma unroll
                for (int d = 1; d < 16; d <<= 1) rsum += __shfl_xor(rsum, d, 64);
                lrow[r] += rsum;
                Ps[w * 640 + (q * 4 + r) * 40 + l15] = (bf16_t)p0;
                Ps[w * 640 + (q * 4 + r) * 40 + 16 + l15] = (bf16_t)p1;
            }
            __syncthreads();

            bf16x8 pf = *(const bf16x8*)&Ps[w * 640 + l15 * 40 + q * 8];
#pragma unroll
            for (int ni = 0; ni < 16; ni++) {
                bf16x8 vf = *(const bf16x8*)&Vs[(ni * 16 + l15) * 40 + q * 8];
                O[ni] = MFMA16x16x32(pf, vf, O[ni]);
            }
        }

        // epilogue: normalized partial ctx (lrow>0 always: either a real key
        // contributed, or fully-masked rows accumulated p=1 terms)
#pragma unroll
        for (int ni = 0; ni < 16; ni++)
#pragma unroll
            for (int r = 0; r < 4; r++) {
                int grow = qr + q * 4 + r;
                Cp[(size_t)grow * 4096 + h * 256 + ni * 16 + l15] =
                    (bf16_t)(O[ni][r] / lrow[r]);
            }
        if (l15 == 0) {
#pragma unroll
            for (int r = 0; r < 4; r++) {
                int row = qr + q * 4 + r;
                float2 v; v.x = mrow[r]; v.y = lrow[r];
                mlp[row * 16 + h] = v;
            }
        }
    }
}

// ---------------------------------------------------------------------------
// Merge split-K partials: out = (c0*w0 + c1*w1)/(w0+w1), w_p = l_p*e^(m_p-mm).
// 8 bf16/thread, grid 4096x256. w0>0 always; dead partials (m=-1e30) -> w=0.
// ---------------------------------------------------------------------------
__global__ __launch_bounds__(256) void merge_ctx(
    const bf16_t* __restrict__ C0, const bf16_t* __restrict__ C1,
    const float2* __restrict__ Ml, bf16_t* __restrict__ Out) {
    size_t i8 = ((size_t)blockIdx.x * 256 + threadIdx.x) * 8;
    int row = (int)(i8 >> 12);
    int h = (int)((i8 >> 8) & 15);
    float2 a = Ml[row * 16 + h];
    float2 b = Ml[2048 * 16 + row * 16 + h];
    float mm = fmaxf(a.x, b.x);
    float w0 = a.y * __expf(a.x - mm);
    float w1 = b.y * __expf(b.x - mm);
    float inv = 1.0f / (w0 + w1);
    w0 *= inv; w1 *= inv;
    bf16x8 x0 = *(const bf16x8*)(C0 + i8);
    bf16x8 x1 = *(const bf16x8*)(C1 + i8);
    bf16_t o[8];
#pragma unroll
    for (int j = 0; j < 8; j++)
        o[j] = (bf16_t)((float)x0[j] * w0 + (float)x1[j] * w1);
    *(uint4*)(Out + i8) = *(const uint4*)o;
}

// ---------------------------------------------------------------------------
// FALLBACK flash attention (round-0 proven, 156us): paired q-tiles
// {bx, 31-bx} sequentially, grid (16,16). Unchanged.
// ---------------------------------------------------------------------------
__global__ __launch_bounds__(256) void attn_kernel(
    const bf16_t* __restrict__ Q, const bf16_t* __restrict__ K,
    const bf16_t* __restrict__ Vt, bf16_t* __restrict__ Ctx) {
    __shared__ bf16_t Ks[32 * 264];
    __shared__ bf16_t Vs[256 * 40];
    __shared__ bf16_t Ps[4 * 16 * 40];
    const int h = blockIdx.y;
    const int t = threadIdx.x, w = t >> 6, l = t & 63, l15 = l & 15, q = l >> 4;

    for (int pass = 0; pass < 2; pass++) {
        const int qt = pass ? (31 - (int)blockIdx.x) : (int)blockIdx.x;
        const int qr = qt * 64 + w * 16;

        bf16x8 qf[8];
        {
            const bf16_t* qp = Q + (size_t)(qr + l15) * 4096 + h * 256 + q * 8;
#pragma unroll
            for (int tt = 0; tt < 8; tt++) qf[tt] = *(const bf16x8*)(qp + tt * 32);
        }
        floatx4 O[16];
#pragma unroll
        for (int i = 0; i < 16; i++) O[i] = floatx4{0.f, 0.f, 0.f, 0.f};
        float mrow[4] = {-1e30f, -1e30f, -1e30f, -1e30f};
        float lrow[4] = {0.f, 0.f, 0.f, 0.f};

        const int nkt = 2 * qt + 2;
        for (int kt = 0; kt < nkt; kt++) {
            __syncthreads();
#pragma unroll
            for (int i = 0; i < 4; i++) {
                int idx = i * 256 + t;
                int key = idx >> 5, d16 = (idx & 31) << 3;
                uint4 v = *(const uint4*)(K + (size_t)(kt * 32 + key) * 4096 + h * 256 + d16);
                *(uint4*)&Ks[key * 264 + d16] = v;
            }
#pragma unroll
            for (int i = 0; i < 4; i++) {
                int idx = i * 256 + t;
                int d = idx >> 2, k8 = (idx & 3) << 3;
                uint4 v = *(const uint4*)(Vt + (size_t)h * 524288 + (size_t)d * 2048 + kt * 32 + k8);
                *(uint4*)&Vs[d * 40 + k8] = v;
            }
            __syncthreads();

            floatx4 sc0 = floatx4{0.f, 0.f, 0.f, 0.f};
            floatx4 sc1 = floatx4{0.f, 0.f, 0.f, 0.f};
#pragma unroll
            for (int tt = 0; tt < 8; tt++) {
                bf16x8 k0f = *(const bf16x8*)&Ks[l15 * 264 + tt * 32 + q * 8];
                bf16x8 k1f = *(const bf16x8*)&Ks[(16 + l15) * 264 + tt * 32 + q * 8];
                sc0 = MFMA16x16x32(qf[tt], k0f, sc0);
                sc1 = MFMA16x16x32(qf[tt], k1f, sc1);
            }

            const bool diag = (kt >= 2 * qt);
#pragma unroll
            for (int r = 0; r < 4; r++) {
                int grow = qr + q * 4 + r;
                float v0 = sc0[r] * 0.0625f;
                float v1 = sc1[r] * 0.0625f;
                if (diag) {
                    if (kt * 32 + l15 > grow) v0 = -1e30f;
                    if (kt * 32 + 16 + l15 > grow) v1 = -1e30f;
                }
                float mx = fmaxf(v0, v1);
#pragma unroll
                for (int d = 1; d < 16; d <<= 1) mx = fmaxf(mx, __shfl_xor(mx, d, 64));
                if (mx > mrow[r]) {
                    float alpha = __expf(mrow[r] - mx);
                    lrow[r] *= alpha;
#pragma unroll
                    for (int ni = 0; ni < 16; ni++) O[ni][r] *= alpha;
                    mrow[r] = mx;
                }
                float p0 = __expf(v0 - mrow[r]), p1 = __expf(v1 - mrow[r]);
                float rsum = p0 + p1;
#pragma unroll
                for (int d = 1; d < 16; d <<= 1) rsum += __shfl_xor(rsum, d, 64);
                lrow[r] += rsum;
                Ps[w * 640 + (q * 4 + r) * 40 + l15] = (bf16_t)p0;
                Ps[w * 640 + (q * 4 + r) * 40 + 16 + l15] = (bf16_t)p1;
            }
            __syncthreads();

            bf16x8 pf = *(const bf16x8*)&Ps[w * 640 + l15 * 40 + q * 8];
#pragma unroll
            for (int ni = 0; ni < 16; ni++) {
                bf16x8 vf = *(const bf16x8*)&Vs[(ni * 16 + l15) * 40 + q * 8];
                O[ni] = MFMA16x16x32(pf, vf, O[ni]);
            }
        }
#pragma unroll
        for (int ni = 0; ni < 16; ni++)
#pragma unroll
            for (int r = 0; r < 4; r++) {
                int grow = qr + q * 4 + r;
                Ctx[(size_t)grow * 4096 + h * 256 + ni * 16 + l15] =
                    (bf16_t)(O[ni][r] / lrow[r]);
            }
    }
}

// ---------------------------------------------------------------------------
// FAST path (ws >= 80MB) layout, phase-aware reuse:
//   [0,16M)  Hb (conv'd hs)        -> Ml (attn)            [Hb dead after V GEMM]
//   [16,48M) Wt (transposes)       -> Cp0/Cp1 (attn)       [Wt dead during attn]
//   [48,64M) Kb (K matrix)         -> Ctx (after merge)    [K dead after attn]
//   [64,80M) Vt                                            | Q in d_out[0,16M)
// FALLBACK (48MB, proven): R0 Wt/Ctx | R1 Vt | R2 K | Q in d_out.
// Branch on ws_size: constant every call -> graph-safe.
// ---------------------------------------------------------------------------
extern "C" void kernel_launch(void* const* d_in, const int* in_sizes, int n_in,
                              void* d_out, int out_size, void* d_ws, size_t ws_size,
                              hipStream_t stream) {
    const void* hs = d_in[0];
    const void* wq = d_in[1];
    const void* wk = d_in[2];
    const void* wv = d_in[3];
    const void* wo = d_in[4];
    const int* pos = (const int*)d_in[5];

    char* ws = (char*)d_ws;
    dim3 tT(256), tb(256);
    dim3 gTfull(64, 64);
    bf16_t* Qb = (bf16_t*)d_out;

    if (ws_size >= ((size_t)80 << 20)) {
        // ---------------- fast path: m97 GEMMs + split-K attn ------------
        bf16_t* Hb  = (bf16_t*)ws;
        float2* Ml  = (float2*)ws;                          // after Hb dead
        bf16_t* Wt  = (bf16_t*)(ws + ((size_t)16 << 20));
        bf16_t* Cp0 = Wt;                                   // after Wt dead
        bf16_t* Cp1 = (bf16_t*)(ws + ((size_t)32 << 20));
        bf16_t* Kb  = (bf16_t*)(ws + ((size_t)48 << 20));
        bf16_t* Ctx = Kb;                                   // after K dead
        bf16_t* Vt  = (bf16_t*)(ws + ((size_t)64 << 20));
        dim3 gG(32, 16);

        conv_hs<<<dim3(4096), tb, 0, stream>>>(hs, Hb);

        transpose_w<<<gTfull, tT, 0, stream>>>(wq, Wt, 0, hs);
        gemm_bf16a<false, false><<<gG, tb, 0, stream>>>(Hb, Wt, Qb, hs);
        transpose_w<<<gTfull, tT, 0, stream>>>(wk, Wt, 0, hs);
        gemm_bf16a<false, false><<<gG, tb, 0, stream>>>(Hb, Wt, Kb, hs);
        transpose_w<<<gTfull, tT, 0, stream>>>(wv, Wt, 0, hs);
        gemm_bf16a<true, false><<<gG, tb, 0, stream>>>(Hb, Wt, Vt, hs);

        rope_qk<<<dim3(4096), tb, 0, stream>>>(Qb, Kb, pos);

        attn_split<<<dim3(16, 16, 2), tb, 0, stream>>>(Qb, Kb, Vt, Cp0, Cp1, Ml);
        merge_ctx<<<dim3(4096), tb, 0, stream>>>(Cp0, Cp1, Ml, Ctx);

        transpose_w<<<gTfull, tT, 0, stream>>>(wo, Wt, 0, hs);  // kills Cp0/Cp1
        gemm_bf16a<false, true><<<gG, tb, 0, stream>>>(Ctx, Wt, d_out, hs);
    } else {
        // ---------------- fallback: proven 48 MB pipeline ----------------
        bf16_t* R0 = (bf16_t*)ws;
        bf16_t* R1 = (bf16_t*)(ws + ((size_t)16 << 20));
        bf16_t* R2 = (bf16_t*)(ws + ((size_t)32 << 20));
        bf16_t* Kb  = R2;
        bf16_t* Vt  = R1;
        bf16_t* Ctx = R0;
        dim3 tG(512);
        dim3 gThalf(64, 32);
        dim3 gGfull(32, 16), gGhalf(16, 16);

        transpose_w<<<gTfull, tT, 0, stream>>>(wq, R0, 0, hs);
        gemm_nt<true, false, false><<<gGfull, tG, 0, stream>>>(hs, R0, Qb, 0, hs);
        transpose_w<<<gTfull, tT, 0, stream>>>(wk, R0, 0, hs);
        gemm_nt<true, false, false><<<gGfull, tG, 0, stream>>>(hs, R0, Kb, 0, hs);
        transpose_w<<<gThalf, tT, 0, stream>>>(wv, R0, 0, hs);
        gemm_nt<true, true, false><<<gGhalf, tG, 0, stream>>>(hs, R0, Vt, 0, hs);
        transpose_w<<<gThalf, tT, 0, stream>>>(wv, R0, 2048, hs);
        gemm_nt<true, true, false><<<gGhalf, tG, 0, stream>>>(hs, R0, Vt, 2048, hs);

        rope_qk<<<dim3(4096), tb, 0, stream>>>(Qb, Kb, pos);

        attn_kernel<<<dim3(16, 16), tb, 0, stream>>>(Qb, Kb, Vt, Ctx);

        transpose_w<<<gThalf, tT, 0, stream>>>(wo, R2, 0, hs);
        gemm_nt<false, false, true><<<gGhalf, tG, 0, stream>>>(Ctx, R2, d_out, 0, hs);
        transpose_w<<<gThalf, tT, 0, stream>>>(wo, R2, 2048, hs);
        gemm_nt<false, false, true><<<gGhalf, tG, 0, stream>>>(Ctx, R2, d_out, 2048, hs);
    }
}

// Round 6
// 761.211 us; speedup vs baseline: 1.0799x; 1.0108x over previous
//
#include <hip/hip_runtime.h>
#include <hip/hip_bf16.h>

typedef __bf16 bf16_t;
typedef __attribute__((ext_vector_type(8))) __bf16 bf16x8;
typedef __attribute__((ext_vector_type(4))) float floatx4;

#define MFMA16x16x32(a, b, c) __builtin_amdgcn_mfma_f32_16x16x32_bf16((a), (b), (c), 0, 0, 0)

__device__ __forceinline__ void glld16(const bf16_t* g, bf16_t* l) {
    __builtin_amdgcn_global_load_lds(
        (const __attribute__((address_space(1))) unsigned int*)g,
        (__attribute__((address_space(3))) unsigned int*)l,
        16, 0, 0);
}

// ---------------------------------------------------------------------------
// On-device dtype sniffer (proven): bf16-pair u32 bits 14..7 are the low
// element's exponent, in [112,142] for N(0,1)-ish data; fp32 -> uniform.
// ---------------------------------------------------------------------------
__device__ __forceinline__ bool detect_bf16(const void* hs) {
    const unsigned* u = (const unsigned*)hs;
    int c = 0;
#pragma unroll 8
    for (int i = 0; i < 64; i++) {
        unsigned e = (u[i] >> 7) & 0xFFu;
        c += (e >= 112u && e <= 142u) ? 1 : 0;
    }
    return c >= 32;
}

// ---------------------------------------------------------------------------
// hs -> bf16 copy/convert (fast path). 8 elems/thread.
// ---------------------------------------------------------------------------
__global__ __launch_bounds__(256) void conv_hs(
    const void* __restrict__ src, bf16_t* __restrict__ dst) {
    const bool isbf = detect_bf16(src);
    size_t i8 = ((size_t)blockIdx.x * 256 + threadIdx.x) * 8;
    if (isbf) {
        *(uint4*)(dst + i8) = *(const uint4*)((const bf16_t*)src + i8);
    } else {
        const float* s = (const float*)src + i8;
        float4 f0 = *(const float4*)s;
        float4 f1 = *(const float4*)(s + 4);
        bf16_t tmp[8];
        tmp[0] = (bf16_t)f0.x; tmp[1] = (bf16_t)f0.y;
        tmp[2] = (bf16_t)f0.z; tmp[3] = (bf16_t)f0.w;
        tmp[4] = (bf16_t)f1.x; tmp[5] = (bf16_t)f1.y;
        tmp[6] = (bf16_t)f1.z; tmp[7] = (bf16_t)f1.w;
        *(uint4*)(dst + i8) = *(const uint4*)tmp;
    }
}

// ---------------------------------------------------------------------------
// 64x64-tiled transpose of W cols [coff, coff+64*gridDim.y) into bf16
// Wt[c][r] (dst row-stride 4096). Source dtype sniffed from hs.
// ---------------------------------------------------------------------------
__global__ __launch_bounds__(256) void transpose_w(
    const void* __restrict__ src, bf16_t* __restrict__ dst,
    int coff, const void* __restrict__ hs) {
    const bool isbf = detect_bf16(hs);
    __shared__ bf16_t T[64 * 68];
    const int r0 = blockIdx.x * 64, c0 = blockIdx.y * 64;
    const int t = threadIdx.x;
#pragma unroll
    for (int i = 0; i < 2; i++) {
        int idx = i * 256 + t;
        int r = idx >> 3, c8 = (idx & 7) << 3;
        bf16_t tmp[8];
        if (isbf) {
            *(uint4*)tmp = *(const uint4*)((const bf16_t*)src +
                              (size_t)(r0 + r) * 4096 + coff + c0 + c8);
        } else {
            const float* s = (const float*)src + (size_t)(r0 + r) * 4096 + coff + c0 + c8;
            float4 f0 = *(const float4*)s;
            float4 f1 = *(const float4*)(s + 4);
            tmp[0] = (bf16_t)f0.x; tmp[1] = (bf16_t)f0.y;
            tmp[2] = (bf16_t)f0.z; tmp[3] = (bf16_t)f0.w;
            tmp[4] = (bf16_t)f1.x; tmp[5] = (bf16_t)f1.y;
            tmp[6] = (bf16_t)f1.z; tmp[7] = (bf16_t)f1.w;
        }
        *(uint2*)&T[r * 68 + c8]     = *(const uint2*)&tmp[0];
        *(uint2*)&T[r * 68 + c8 + 4] = *(const uint2*)&tmp[4];
    }
    __syncthreads();
#pragma unroll
    for (int i = 0; i < 2; i++) {
        int idx = i * 256 + t;
        int c = idx >> 3, r8 = (idx & 7) << 3;
        bf16_t tmp[8];
#pragma unroll
        for (int j = 0; j < 8; j++) tmp[j] = T[(r8 + j) * 68 + c];
        *(uint4*)(dst + (size_t)(c0 + c) * 4096 + r0 + r8) = *(const uint4*)tmp;
    }
}

// ---------------------------------------------------------------------------
// FAST-PATH GEMM (m97 structure, bf16 A): C[2048,4096] = A @ Bt^T.
// ---------------------------------------------------------------------------
template <bool TV, bool C32>
__global__ __launch_bounds__(256, 2) void gemm_bf16a(
    const bf16_t* __restrict__ A, const bf16_t* __restrict__ Bt,
    void* __restrict__ Cout, const void* __restrict__ hs) {
    constexpr int K = 4096;
    __shared__ bf16_t As[128 * 32];
    __shared__ bf16_t Bs[128 * 32];
    const bool isbf = C32 ? detect_bf16(hs) : true;
    const int t = threadIdx.x;
    const int w = t >> 6, l = t & 63, l15 = l & 15, q = l >> 4;
    const int m0 = blockIdx.y * 128, n0 = blockIdx.x * 128;
    const int wm = (w >> 1) * 64, wn = (w & 1) * 64;
    floatx4 acc[4][4];
#pragma unroll
    for (int mi = 0; mi < 4; mi++)
#pragma unroll
        for (int ni = 0; ni < 4; ni++) acc[mi][ni] = floatx4{0.f, 0.f, 0.f, 0.f};

    const bf16_t* ga = A + (size_t)(m0 + (t >> 2)) * K + ((t & 3) << 3);
    const bf16_t* gb = Bt + (size_t)(n0 + (t >> 2)) * K + ((t & 3) << 3);
    bf16_t* lA = &As[(t >> 2) * 32 + ((t & 3) << 3)];
    bf16_t* lB = &Bs[(t >> 2) * 32 + ((t & 3) << 3)];

    for (int k0 = 0; k0 < K; k0 += 32) {
        __syncthreads();
        glld16(ga, lA);
        glld16(ga + (size_t)64 * K, lA + 64 * 32);
        glld16(gb, lB);
        glld16(gb + (size_t)64 * K, lB + 64 * 32);
        ga += 32; gb += 32;
        __syncthreads();
        bf16x8 af[4], bfr[4];
#pragma unroll
        for (int i = 0; i < 4; i++)
            af[i] = *(const bf16x8*)&As[(wm + i * 16 + l15) * 32 + q * 8];
#pragma unroll
        for (int i = 0; i < 4; i++)
            bfr[i] = *(const bf16x8*)&Bs[(wn + i * 16 + l15) * 32 + q * 8];
#pragma unroll
        for (int mi = 0; mi < 4; mi++)
#pragma unroll
            for (int ni = 0; ni < 4; ni++)
                acc[mi][ni] = MFMA16x16x32(af[mi], bfr[ni], acc[mi][ni]);
    }

    if (TV) {
        bf16_t* C = (bf16_t*)Cout;
#pragma unroll
        for (int mi = 0; mi < 4; mi++) {
            int s_base = m0 + wm + mi * 16 + q * 4;
#pragma unroll
            for (int ni = 0; ni < 4; ni++) {
                int e = n0 + wn + ni * 16 + l15;
                int h = e >> 8, dd = e & 255;
                bf16_t o4[4];
#pragma unroll
                for (int r = 0; r < 4; r++) o4[r] = (bf16_t)acc[mi][ni][r];
                *(uint2*)(C + (size_t)h * 524288 + (size_t)dd * 2048 + s_base) =
                    *(const uint2*)o4;
            }
        }
    } else if (C32 && !isbf) {
        float* C = (float*)Cout;
#pragma unroll
        for (int mi = 0; mi < 4; mi++)
#pragma unroll
            for (int ni = 0; ni < 4; ni++)
#pragma unroll
                for (int r = 0; r < 4; r++) {
                    int row = m0 + wm + mi * 16 + q * 4 + r;
                    int col = n0 + wn + ni * 16 + l15;
                    C[(size_t)row * 4096 + col] = acc[mi][ni][r];
                }
    } else {
        bf16_t* C = (bf16_t*)Cout;
#pragma unroll
        for (int mi = 0; mi < 4; mi++)
#pragma unroll
            for (int ni = 0; ni < 4; ni++)
#pragma unroll
                for (int r = 0; r < 4; r++) {
                    int row = m0 + wm + mi * 16 + q * 4 + r;
                    int col = n0 + wn + ni * 16 + l15;
                    C[(size_t)row * 4096 + col] = (bf16_t)acc[mi][ni][r];
                }
    }
}

// ---------------------------------------------------------------------------
// FALLBACK GEMM (proven): 512 threads, dbuf, register-A (fp32-able).
// ---------------------------------------------------------------------------
template <bool AHS, bool TV, bool CMAY32>
__global__ __launch_bounds__(512, 4) void gemm_nt(
    const void* __restrict__ Ain, const bf16_t* __restrict__ Bt,
    void* __restrict__ Cout, int n_off, const void* __restrict__ hs) {
    constexpr int K = 4096, NITER = K / 32;
    const bool isbf = (AHS || CMAY32) ? detect_bf16(hs) : true;
    __shared__ bf16_t As[2][128 * 32];
    __shared__ bf16_t Bs[2][128 * 32];
    const int t = threadIdx.x;
    const int w = t >> 6, l = t & 63, l15 = l & 15, q = l >> 4;
    const int m0 = blockIdx.y * 128, n0 = blockIdx.x * 128;
    const int wm = (w >> 2) * 64, wn = (w & 3) * 32;
    floatx4 acc[4][2];
#pragma unroll
    for (int mi = 0; mi < 4; mi++)
#pragma unroll
        for (int ni = 0; ni < 2; ni++) acc[mi][ni] = floatx4{0.f, 0.f, 0.f, 0.f};

    const int ar = t >> 2, ac = (t & 3) << 3;
    const bf16_t* Ab = (const bf16_t*)Ain;
    const float*  Af = (const float*)Ain;
    const bf16_t* gb = Bt + (size_t)(n0 + ar) * K + ac;
    const int lofs = ar * 32 + ac;

    bf16_t areg[8];
    float  freg[8];

    auto loadA = [&](int ki) {
        if (AHS && !isbf) {
            const float* s = Af + (size_t)(m0 + ar) * K + ki * 32 + ac;
            *(float4*)&freg[0] = *(const float4*)s;
            *(float4*)&freg[4] = *(const float4*)(s + 4);
        } else {
            *(uint4*)areg = *(const uint4*)(Ab + (size_t)(m0 + ar) * K + ki * 32 + ac);
        }
    };
    auto writeA = [&](int p) {
        if (AHS && !isbf) {
            bf16_t tmp[8];
#pragma unroll
            for (int j = 0; j < 8; j++) tmp[j] = (bf16_t)freg[j];
            *(uint4*)&As[p][lofs] = *(const uint4*)tmp;
        } else {
            *(uint4*)&As[p][lofs] = *(const uint4*)areg;
        }
    };

    loadA(0);
    writeA(0);
    glld16(gb, &Bs[0][lofs]);
    loadA(1);

    int p = 0;
    for (int i = 0; i < NITER; i++) {
        __syncthreads();
        if (i + 1 < NITER) {
            glld16(gb + (i + 1) * 32, &Bs[p ^ 1][lofs]);
            writeA(p ^ 1);
            if (i + 2 < NITER) loadA(i + 2);
        }
        bf16x8 af[4], bfr[2];
#pragma unroll
        for (int ii = 0; ii < 4; ii++)
            af[ii] = *(const bf16x8*)&As[p][(wm + ii * 16 + l15) * 32 + q * 8];
#pragma unroll
        for (int jj = 0; jj < 2; jj++)
            bfr[jj] = *(const bf16x8*)&Bs[p][(wn + jj * 16 + l15) * 32 + q * 8];
#pragma unroll
        for (int mi = 0; mi < 4; mi++)
#pragma unroll
            for (int ni = 0; ni < 2; ni++)
                acc[mi][ni] = MFMA16x16x32(af[mi], bfr[ni], acc[mi][ni]);
        p ^= 1;
    }

    if (TV) {
        bf16_t* C = (bf16_t*)Cout;
#pragma unroll
        for (int mi = 0; mi < 4; mi++) {
            int s_base = m0 + wm + mi * 16 + q * 4;
#pragma unroll
            for (int ni = 0; ni < 2; ni++) {
                int e = n_off + n0 + wn + ni * 16 + l15;
                int h = e >> 8, dd = e & 255;
                bf16_t o4[4];
#pragma unroll
                for (int r = 0; r < 4; r++) o4[r] = (bf16_t)acc[mi][ni][r];
                *(uint2*)(C + (size_t)h * 524288 + (size_t)dd * 2048 + s_base) =
                    *(const uint2*)o4;
            }
        }
    } else if (CMAY32 && !isbf) {
        float* C = (float*)Cout;
#pragma unroll
        for (int mi = 0; mi < 4; mi++)
#pragma unroll
            for (int ni = 0; ni < 2; ni++)
#pragma unroll
                for (int r = 0; r < 4; r++) {
                    int row = m0 + wm + mi * 16 + q * 4 + r;
                    int col = n_off + n0 + wn + ni * 16 + l15;
                    C[(size_t)row * 4096 + col] = acc[mi][ni][r];
                }
    } else {
        bf16_t* C = (bf16_t*)Cout;
#pragma unroll
        for (int mi = 0; mi < 4; mi++)
#pragma unroll
            for (int ni = 0; ni < 2; ni++)
#pragma unroll
                for (int r = 0; r < 4; r++) {
                    int row = m0 + wm + mi * 16 + q * 4 + r;
                    int col = n_off + n0 + wn + ni * 16 + l15;
                    C[(size_t)row * 4096 + col] = (bf16_t)acc[mi][ni][r];
                }
    }
}

// ---------------------------------------------------------------------------
// GPT-J interleaved RoPE on first 64 dims of each 256-dim head, Q and K.
// ---------------------------------------------------------------------------
__global__ __launch_bounds__(256) void rope_qk(
    bf16_t* __restrict__ Q, bf16_t* __restrict__ K,
    const int* __restrict__ pos_ids) {
    int tid = blockIdx.x * 256 + threadIdx.x;
    int i = tid & 31;
    int h = (tid >> 5) & 15;
    int s = tid >> 9;
    float p = (float)pos_ids[s];
    float inv = __expf(-(float)i * 0.28782313662425572f);  // 10000^(-i/32)
    float ang = p * inv;
    float sn, cs;
    __sincosf(ang, &sn, &cs);
    size_t base = (size_t)s * 4096 + h * 256 + 2 * i;
    float q0 = (float)Q[base], q1 = (float)Q[base + 1];
    Q[base]     = (bf16_t)(q0 * cs - q1 * sn);
    Q[base + 1] = (bf16_t)(q1 * cs + q0 * sn);
    float k0 = (float)K[base], k1 = (float)K[base + 1];
    K[base]     = (bf16_t)(k0 * cs - k1 * sn);
    K[base + 1] = (bf16_t)(k1 * cs + k0 * sn);
}

// ---------------------------------------------------------------------------
// Flash attention 3-WAY SPLIT-K: pair {bx, 31-bx} has exactly 66 k-tile
// units; block (bx, h, s) takes units [22s, 22s+22) -- perfectly uniform,
// 768 blocks, 3 resident/CU (LDS 3x42.5KB=127.5 <= 160KB; VGPR 96*3 waves
// <= 512/SIMD). A block's range may span both q-tiles -> up to 2 segments;
// each segment emits normalized ctx into slot s + (m,l). Dead segments
// write (m=-1e30, l=0) so every Ml entry is defined; merge3 guards ctx
// reads with w>0 selects (uninit partial-ctx garbage, even NaN, never
// contributes). T5 setprio around MFMA clusters (independent blocks at
// different phases = m191's attn regime).
// ---------------------------------------------------------------------------
__global__ __launch_bounds__(256, 3) void attn_split3(
    const bf16_t* __restrict__ Q, const bf16_t* __restrict__ K,
    const bf16_t* __restrict__ Vt, bf16_t* __restrict__ C0,
    bf16_t* __restrict__ C1, bf16_t* __restrict__ C2,
    float2* __restrict__ Ml) {
    __shared__ bf16_t Ks[32 * 264];
    __shared__ bf16_t Vs[256 * 40];
    __shared__ bf16_t Ps[4 * 16 * 40];
    const int h = blockIdx.y;
    const int sp = blockIdx.z;
    const int t = threadIdx.x, w = t >> 6, l = t & 63, l15 = l & 15, q = l >> 4;
    bf16_t* __restrict__ Cp = (sp == 0) ? C0 : ((sp == 1) ? C1 : C2);
    float2* __restrict__ mlp = Ml + (size_t)sp * (2048 * 16);

    const int bx = blockIdx.x;
    const int ntA = 2 * bx + 2;
    const int ubeg = 22 * sp, uend = ubeg + 22;

    for (int seg = 0; seg < 2; seg++) {
        const int qt = seg ? (31 - bx) : bx;
        const int qr = qt * 64 + w * 16;
        int ktb, kte;
        if (seg == 0) {           // qtA: units [0, ntA) map kt = unit
            ktb = ubeg;
            kte = (ntA < uend) ? ntA : uend;
        } else {                  // qtB: units [ntA, 66) map kt = unit - ntA
            ktb = ((ntA > ubeg) ? ntA : ubeg) - ntA;
            kte = uend - ntA;
        }

        if (kte <= ktb) {         // empty segment (block-uniform branch)
            if (l15 == 0) {
#pragma unroll
                for (int r = 0; r < 4; r++) {
                    int row = qr + q * 4 + r;
                    float2 v; v.x = -1e30f; v.y = 0.f;
                    mlp[row * 16 + h] = v;
                }
            }
            continue;
        }

        bf16x8 qf[8];
        {
            const bf16_t* qp = Q + (size_t)(qr + l15) * 4096 + h * 256 + q * 8;
#pragma unroll
            for (int tt = 0; tt < 8; tt++) qf[tt] = *(const bf16x8*)(qp + tt * 32);
        }
        floatx4 O[16];
#pragma unroll
        for (int i = 0; i < 16; i++) O[i] = floatx4{0.f, 0.f, 0.f, 0.f};
        float mrow[4] = {-1e30f, -1e30f, -1e30f, -1e30f};
        float lrow[4] = {0.f, 0.f, 0.f, 0.f};

        for (int kt = ktb; kt < kte; kt++) {
            __syncthreads();
#pragma unroll
            for (int i = 0; i < 4; i++) {
                int idx = i * 256 + t;
                int key = idx >> 5, d16 = (idx & 31) << 3;
                uint4 v = *(const uint4*)(K + (size_t)(kt * 32 + key) * 4096 + h * 256 + d16);
                *(uint4*)&Ks[key * 264 + d16] = v;
            }
#pragma unroll
            for (int i = 0; i < 4; i++) {
                int idx = i * 256 + t;
                int d = idx >> 2, k8 = (idx & 3) << 3;
                uint4 v = *(const uint4*)(Vt + (size_t)h * 524288 + (size_t)d * 2048 + kt * 32 + k8);
                *(uint4*)&Vs[d * 40 + k8] = v;
            }
            __syncthreads();

            floatx4 sc0 = floatx4{0.f, 0.f, 0.f, 0.f};
            floatx4 sc1 = floatx4{0.f, 0.f, 0.f, 0.f};
            __builtin_amdgcn_s_setprio(1);
#pragma unroll
            for (int tt = 0; tt < 8; tt++) {
                bf16x8 k0f = *(const bf16x8*)&Ks[l15 * 264 + tt * 32 + q * 8];
                bf16x8 k1f = *(const bf16x8*)&Ks[(16 + l15) * 264 + tt * 32 + q * 8];
                sc0 = MFMA16x16x32(qf[tt], k0f, sc0);
                sc1 = MFMA16x16x32(qf[tt], k1f, sc1);
            }
            __builtin_amdgcn_s_setprio(0);

            const bool diag = (kt >= 2 * qt);
#pragma unroll
            for (int r = 0; r < 4; r++) {
                int grow = qr + q * 4 + r;
                float v0 = sc0[r] * 0.0625f;
                float v1 = sc1[r] * 0.0625f;
                if (diag) {
                    if (kt * 32 + l15 > grow) v0 = -1e30f;
                    if (kt * 32 + 16 + l15 > grow) v1 = -1e30f;
                }
                float mx = fmaxf(v0, v1);
#pragma unroll
                for (int d = 1; d < 16; d <<= 1) mx = fmaxf(mx, __shfl_xor(mx, d, 64));
                if (mx > mrow[r]) {  // bit-exact skip: alpha==1 otherwise
                    float alpha = __expf(mrow[r] - mx);
                    lrow[r] *= alpha;
#pragma unroll
                    for (int ni = 0; ni < 16; ni++) O[ni][r] *= alpha;
                    mrow[r] = mx;
                }
                float p0 = __expf(v0 - mrow[r]), p1 = __expf(v1 - mrow[r]);
                float rsum = p0 + p1;
#pragma unroll
                for (int d = 1; d < 16; d <<= 1) rsum += __shfl_xor(rsum, d, 64);
                lrow[r] += rsum;
                Ps[w * 640 + (q * 4 + r) * 40 + l15] = (bf16_t)p0;
                Ps[w * 640 + (q * 4 + r) * 40 + 16 + l15] = (bf16_t)p1;
            }
            __syncthreads();

            bf16x8 pf = *(const bf16x8*)&Ps[w * 640 + l15 * 40 + q * 8];
            __builtin_amdgcn_s_setprio(1);
#pragma unroll
            for (int ni = 0; ni < 16; ni++) {
                bf16x8 vf = *(const bf16x8*)&Vs[(ni * 16 + l15) * 40 + q * 8];
                O[ni] = MFMA16x16x32(pf, vf, O[ni]);
            }
            __builtin_amdgcn_s_setprio(0);
        }

        // epilogue: normalized partial ctx (lrow>0: real keys or p=1 terms)
#pragma unroll
        for (int ni = 0; ni < 16; ni++)
#pragma unroll
            for (int r = 0; r < 4; r++) {
                int grow = qr + q * 4 + r;
                Cp[(size_t)grow * 4096 + h * 256 + ni * 16 + l15] =
                    (bf16_t)(O[ni][r] / lrow[r]);
            }
        if (l15 == 0) {
#pragma unroll
            for (int r = 0; r < 4; r++) {
                int row = qr + q * 4 + r;
                float2 v; v.x = mrow[r]; v.y = lrow[r];
                mlp[row * 16 + h] = v;
            }
        }
    }
}

// ---------------------------------------------------------------------------
// Merge 3 split-K partials. w_i = l_i*e^(m_i-mm); dead slots have l=0 ->
// w=0; ctx reads guarded by w>0 (uninit garbage never contributes).
// ---------------------------------------------------------------------------
__global__ __launch_bounds__(256) void merge3(
    const bf16_t* __restrict__ C0, const bf16_t* __restrict__ C1,
    const bf16_t* __restrict__ C2, const float2* __restrict__ Ml,
    bf16_t* __restrict__ Out) {
    size_t i8 = ((size_t)blockIdx.x * 256 + threadIdx.x) * 8;
    int row = (int)(i8 >> 12);
    int h = (int)((i8 >> 8) & 15);
    float2 a = Ml[row * 16 + h];
    float2 b = Ml[2048 * 16 + row * 16 + h];
    float2 c = Ml[2 * 2048 * 16 + row * 16 + h];
    float ma = (a.y > 0.f) ? a.x : -1e30f;
    float mb = (b.y > 0.f) ? b.x : -1e30f;
    float mc = (c.y > 0.f) ? c.x : -1e30f;
    float mm = fmaxf(ma, fmaxf(mb, mc));
    float w0 = a.y * __expf(ma - mm);
    float w1 = b.y * __expf(mb - mm);
    float w2 = c.y * __expf(mc - mm);
    float inv = 1.0f / (w0 + w1 + w2);
    w0 *= inv; w1 *= inv; w2 *= inv;
    bf16x8 x0 = *(const bf16x8*)(C0 + i8);
    bf16x8 x1 = *(const bf16x8*)(C1 + i8);
    bf16x8 x2 = *(const bf16x8*)(C2 + i8);
    bf16_t o[8];
#pragma unroll
    for (int j = 0; j < 8; j++) {
        float t0 = (w0 > 0.f) ? (float)x0[j] * w0 : 0.f;
        float t1 = (w1 > 0.f) ? (float)x1[j] * w1 : 0.f;
        float t2 = (w2 > 0.f) ? (float)x2[j] * w2 : 0.f;
        o[j] = (bf16_t)(t0 + t1 + t2);
    }
    *(uint4*)(Out + i8) = *(const uint4*)o;
}

// ---------------------------------------------------------------------------
// 2-way split-K attention (round-5 proven, 122us) -- used when d_out has no
// spare room for the 3-slot Ml array. Grid (16,16,2).
// ---------------------------------------------------------------------------
__global__ __launch_bounds__(256, 2) void attn_split(
    const bf16_t* __restrict__ Q, const bf16_t* __restrict__ K,
    const bf16_t* __restrict__ Vt, bf16_t* __restrict__ C0,
    bf16_t* __restrict__ C1, float2* __restrict__ Ml) {
    __shared__ bf16_t Ks[32 * 264];
    __shared__ bf16_t Vs[256 * 40];
    __shared__ bf16_t Ps[4 * 16 * 40];
    const int h = blockIdx.y;
    const int half = blockIdx.z;
    const int t = threadIdx.x, w = t >> 6, l = t & 63, l15 = l & 15, q = l >> 4;
    bf16_t* __restrict__ Cp = half ? C1 : C0;
    float2* __restrict__ mlp = Ml + (size_t)half * (2048 * 16);

    for (int seg = 0; seg < 2; seg++) {
        const int qt = seg ? (31 - (int)blockIdx.x) : (int)blockIdx.x;
        const int qr = qt * 64 + w * 16;
        const int nt2 = qt + 1;
        const int ktbeg = half * nt2, ktend = ktbeg + nt2;

        bf16x8 qf[8];
        {
            const bf16_t* qp = Q + (size_t)(qr + l15) * 4096 + h * 256 + q * 8;
#pragma unroll
            for (int tt = 0; tt < 8; tt++) qf[tt] = *(const bf16x8*)(qp + tt * 32);
        }
        floatx4 O[16];
#pragma unroll
        for (int i = 0; i < 16; i++) O[i] = floatx4{0.f, 0.f, 0.f, 0.f};
        float mrow[4] = {-1e30f, -1e30f, -1e30f, -1e30f};
        float lrow[4] = {0.f, 0.f, 0.f, 0.f};

        for (int kt = ktbeg; kt < ktend; kt++) {
            __syncthreads();
#pragma unroll
            for (int i = 0; i < 4; i++) {
                int idx = i * 256 + t;
                int key = idx >> 5, d16 = (idx & 31) << 3;
                uint4 v = *(const uint4*)(K + (size_t)(kt * 32 + key) * 4096 + h * 256 + d16);
                *(uint4*)&Ks[key * 264 + d16] = v;
            }
#pragma unroll
            for (int i = 0; i < 4; i++) {
                int idx = i * 256 + t;
                int d = idx >> 2, k8 = (idx & 3) << 3;
                uint4 v = *(const uint4*)(Vt + (size_t)h * 524288 + (size_t)d * 2048 + kt * 32 + k8);
                *(uint4*)&Vs[d * 40 + k8] = v;
            }
            __syncthreads();

            floatx4 sc0 = floatx4{0.f, 0.f, 0.f, 0.f};
            floatx4 sc1 = floatx4{0.f, 0.f, 0.f, 0.f};
#pragma unroll
            for (int tt = 0; tt < 8; tt++) {
                bf16x8 k0f = *(const bf16x8*)&Ks[l15 * 264 + tt * 32 + q * 8];
                bf16x8 k1f = *(const bf16x8*)&Ks[(16 + l15) * 264 + tt * 32 + q * 8];
                sc0 = MFMA16x16x32(qf[tt], k0f, sc0);
                sc1 = MFMA16x16x32(qf[tt], k1f, sc1);
            }

            const bool diag = (kt >= 2 * qt);
#pragma unroll
            for (int r = 0; r < 4; r++) {
                int grow = qr + q * 4 + r;
                float v0 = sc0[r] * 0.0625f;
                float v1 = sc1[r] * 0.0625f;
                if (diag) {
                    if (kt * 32 + l15 > grow) v0 = -1e30f;
                    if (kt * 32 + 16 + l15 > grow) v1 = -1e30f;
                }
                float mx = fmaxf(v0, v1);
#pragma unroll
                for (int d = 1; d < 16; d <<= 1) mx = fmaxf(mx, __shfl_xor(mx, d, 64));
                if (mx > mrow[r]) {
                    float alpha = __expf(mrow[r] - mx);
                    lrow[r] *= alpha;
#pragma unroll
                    for (int ni = 0; ni < 16; ni++) O[ni][r] *= alpha;
                    mrow[r] = mx;
                }
                float p0 = __expf(v0 - mrow[r]), p1 = __expf(v1 - mrow[r]);
                float rsum = p0 + p1;
#pragma unroll
                for (int d = 1; d < 16; d <<= 1) rsum += __shfl_xor(rsum, d, 64);
                lrow[r] += rsum;
                Ps[w * 640 + (q * 4 + r) * 40 + l15] = (bf16_t)p0;
                Ps[w * 640 + (q * 4 + r) * 40 + 16 + l15] = (bf16_t)p1;
            }
            __syncthreads();

            bf16x8 pf = *(const bf16x8*)&Ps[w * 640 + l15 * 40 + q * 8];
#pragma unroll
            for (int ni = 0; ni < 16; ni++) {
                bf16x8 vf = *(const bf16x8*)&Vs[(ni * 16 + l15) * 40 + q * 8];
                O[ni] = MFMA16x16x32(pf, vf, O[ni]);
            }
        }

#pragma unroll
        for (int ni = 0; ni < 16; ni++)
#pragma unroll
            for (int r = 0; r < 4; r++) {
                int grow = qr + q * 4 + r;
                Cp[(size_t)grow * 4096 + h * 256 + ni * 16 + l15] =
                    (bf16_t)(O[ni][r] / lrow[r]);
            }
        if (l15 == 0) {
#pragma unroll
            for (int r = 0; r < 4; r++) {
                int row = qr + q * 4 + r;
                float2 v; v.x = mrow[r]; v.y = lrow[r];
                mlp[row * 16 + h] = v;
            }
        }
    }
}

__global__ __launch_bounds__(256) void merge_ctx(
    const bf16_t* __restrict__ C0, const bf16_t* __restrict__ C1,
    const float2* __restrict__ Ml, bf16_t* __restrict__ Out) {
    size_t i8 = ((size_t)blockIdx.x * 256 + threadIdx.x) * 8;
    int row = (int)(i8 >> 12);
    int h = (int)((i8 >> 8) & 15);
    float2 a = Ml[row * 16 + h];
    float2 b = Ml[2048 * 16 + row * 16 + h];
    float mm = fmaxf(a.x, b.x);
    float w0 = a.y * __expf(a.x - mm);
    float w1 = b.y * __expf(b.x - mm);
    float inv = 1.0f / (w0 + w1);
    w0 *= inv; w1 *= inv;
    bf16x8 x0 = *(const bf16x8*)(C0 + i8);
    bf16x8 x1 = *(const bf16x8*)(C1 + i8);
    bf16_t o[8];
#pragma unroll
    for (int j = 0; j < 8; j++)
        o[j] = (bf16_t)((float)x0[j] * w0 + (float)x1[j] * w1);
    *(uint4*)(Out + i8) = *(const uint4*)o;
}

// ---------------------------------------------------------------------------
// FALLBACK flash attention (round-0 proven, 156us).
// ---------------------------------------------------------------------------
__global__ __launch_bounds__(256) void attn_kernel(
    const bf16_t* __restrict__ Q, const bf16_t* __restrict__ K,
    const bf16_t* __restrict__ Vt, bf16_t* __restrict__ Ctx) {
    __shared__ bf16_t Ks[32 * 264];
    __shared__ bf16_t Vs[256 * 40];
    __shared__ bf16_t Ps[4 * 16 * 40];
    const int h = blockIdx.y;
    const int t = threadIdx.x, w = t >> 6, l = t & 63, l15 = l & 15, q = l >> 4;

    for (int pass = 0; pass < 2; pass++) {
        const int qt = pass ? (31 - (int)blockIdx.x) : (int)blockIdx.x;
        const int qr = qt * 64 + w * 16;

        bf16x8 qf[8];
        {
            const bf16_t* qp = Q + (size_t)(qr + l15) * 4096 + h * 256 + q * 8;
#pragma unroll
            for (int tt = 0; tt < 8; tt++) qf[tt] = *(const bf16x8*)(qp + tt * 32);
        }
        floatx4 O[16];
#pragma unroll
        for (int i = 0; i < 16; i++) O[i] = floatx4{0.f, 0.f, 0.f, 0.f};
        float mrow[4] = {-1e30f, -1e30f, -1e30f, -1e30f};
        float lrow[4] = {0.f, 0.f, 0.f, 0.f};

        const int nkt = 2 * qt + 2;
        for (int kt = 0; kt < nkt; kt++) {
            __syncthreads();
#pragma unroll
            for (int i = 0; i < 4; i++) {
                int idx = i * 256 + t;
                int key = idx >> 5, d16 = (idx & 31) << 3;
                uint4 v = *(const uint4*)(K + (size_t)(kt * 32 + key) * 4096 + h * 256 + d16);
                *(uint4*)&Ks[key * 264 + d16] = v;
            }
#pragma unroll
            for (int i = 0; i < 4; i++) {
                int idx = i * 256 + t;
                int d = idx >> 2, k8 = (idx & 3) << 3;
                uint4 v = *(const uint4*)(Vt + (size_t)h * 524288 + (size_t)d * 2048 + kt * 32 + k8);
                *(uint4*)&Vs[d * 40 + k8] = v;
            }
            __syncthreads();

            floatx4 sc0 = floatx4{0.f, 0.f, 0.f, 0.f};
            floatx4 sc1 = floatx4{0.f, 0.f, 0.f, 0.f};
#pragma unroll
            for (int tt = 0; tt < 8; tt++) {
                bf16x8 k0f = *(const bf16x8*)&Ks[l15 * 264 + tt * 32 + q * 8];
                bf16x8 k1f = *(const bf16x8*)&Ks[(16 + l15) * 264 + tt * 32 + q * 8];
                sc0 = MFMA16x16x32(qf[tt], k0f, sc0);
                sc1 = MFMA16x16x32(qf[tt], k1f, sc1);
            }

            const bool diag = (kt >= 2 * qt);
#pragma unroll
            for (int r = 0; r < 4; r++) {
                int grow = qr + q * 4 + r;
                float v0 = sc0[r] * 0.0625f;
                float v1 = sc1[r] * 0.0625f;
                if (diag) {
                    if (kt * 32 + l15 > grow) v0 = -1e30f;
                    if (kt * 32 + 16 + l15 > grow) v1 = -1e30f;
                }
                float mx = fmaxf(v0, v1);
#pragma unroll
                for (int d = 1; d < 16; d <<= 1) mx = fmaxf(mx, __shfl_xor(mx, d, 64));
                if (mx > mrow[r]) {
                    float alpha = __expf(mrow[r] - mx);
                    lrow[r] *= alpha;
#pragma unroll
                    for (int ni = 0; ni < 16; ni++) O[ni][r] *= alpha;
                    mrow[r] = mx;
                }
                float p0 = __expf(v0 - mrow[r]), p1 = __expf(v1 - mrow[r]);
                float rsum = p0 + p1;
#pragma unroll
                for (int d = 1; d < 16; d <<= 1) rsum += __shfl_xor(rsum, d, 64);
                lrow[r] += rsum;
                Ps[w * 640 + (q * 4 + r) * 40 + l15] = (bf16_t)p0;
                Ps[w * 640 + (q * 4 + r) * 40 + 16 + l15] = (bf16_t)p1;
            }
            __syncthreads();

            bf16x8 pf = *(const bf16x8*)&Ps[w * 640 + l15 * 40 + q * 8];
#pragma unroll
            for (int ni = 0; ni < 16; ni++) {
                bf16x8 vf = *(const bf16x8*)&Vs[(ni * 16 + l15) * 40 + q * 8];
                O[ni] = MFMA16x16x32(pf, vf, O[ni]);
            }
        }
#pragma unroll
        for (int ni = 0; ni < 16; ni++)
#pragma unroll
            for (int r = 0; r < 4; r++) {
                int grow = qr + q * 4 + r;
                Ctx[(size_t)grow * 4096 + h * 256 + ni * 16 + l15] =
                    (bf16_t)(O[ni][r] / lrow[r]);
            }
    }
}

// ---------------------------------------------------------------------------
// FAST path (ws >= 80MB) layout, phase-aware reuse:
//   [0,16M)  Hb (conv'd hs)   -> Cp2 (attn)       [Hb dead after V GEMM]
//   [16,48M) Wt (transposes)  -> Cp0/Cp1 (attn)   [Wt dead during attn]
//   [48,64M) Kb (K matrix)    -> Ctx (post-merge) [K dead after attn]
//   [64,80M) Vt               | Q in d_out[0,16M)
//   Ml (3x0.25M float2) in d_out[16M,16.75M) -- requires out_size>=17M
//   (fp32 output = 32MB; Ml dead before final GEMM overwrites d_out).
//   If out_size < 17M: round-5 2-way split (Ml in Hb region).
// FALLBACK (48MB, proven): R0 Wt/Ctx | R1 Vt | R2 K | Q in d_out.
// All branches on ws_size/out_size: constant every call -> graph-safe.
// ---------------------------------------------------------------------------
extern "C" void kernel_launch(void* const* d_in, const int* in_sizes, int n_in,
                              void* d_out, int out_size, void* d_ws, size_t ws_size,
                              hipStream_t stream) {
    const void* hs = d_in[0];
    const void* wq = d_in[1];
    const void* wk = d_in[2];
    const void* wv = d_in[3];
    const void* wo = d_in[4];
    const int* pos = (const int*)d_in[5];

    char* ws = (char*)d_ws;
    dim3 tT(256), tb(256);
    dim3 gTfull(64, 64);
    bf16_t* Qb = (bf16_t*)d_out;

    if (ws_size >= ((size_t)80 << 20)) {
        // ---------------- fast path: m97 GEMMs + split-K attn ------------
        bf16_t* Hb  = (bf16_t*)ws;
        bf16_t* Cp2 = Hb;                                   // after Hb dead
        float2* Ml2 = (float2*)ws;                          // 2-way fallback Ml
        bf16_t* Wt  = (bf16_t*)(ws + ((size_t)16 << 20));
        bf16_t* Cp0 = Wt;                                   // after Wt dead
        bf16_t* Cp1 = (bf16_t*)(ws + ((size_t)32 << 20));
        bf16_t* Kb  = (bf16_t*)(ws + ((size_t)48 << 20));
        bf16_t* Ctx = Kb;                                   // after K dead
        bf16_t* Vt  = (bf16_t*)(ws + ((size_t)64 << 20));
        dim3 gG(32, 16);
        const bool can3 = out_size >= (17 << 20);
        float2* Ml3 = (float2*)((char*)d_out + ((size_t)16 << 20));

        conv_hs<<<dim3(4096), tb, 0, stream>>>(hs, Hb);

        transpose_w<<<gTfull, tT, 0, stream>>>(wq, Wt, 0, hs);
        gemm_bf16a<false, false><<<gG, tb, 0, stream>>>(Hb, Wt, Qb, hs);
        transpose_w<<<gTfull, tT, 0, stream>>>(wk, Wt, 0, hs);
        gemm_bf16a<false, false><<<gG, tb, 0, stream>>>(Hb, Wt, Kb, hs);
        transpose_w<<<gTfull, tT, 0, stream>>>(wv, Wt, 0, hs);
        gemm_bf16a<true, false><<<gG, tb, 0, stream>>>(Hb, Wt, Vt, hs);

        rope_qk<<<dim3(4096), tb, 0, stream>>>(Qb, Kb, pos);

        if (can3) {
            attn_split3<<<dim3(16, 16, 3), tb, 0, stream>>>(Qb, Kb, Vt,
                                                            Cp0, Cp1, Cp2, Ml3);
            merge3<<<dim3(4096), tb, 0, stream>>>(Cp0, Cp1, Cp2, Ml3, Ctx);
        } else {
            attn_split<<<dim3(16, 16, 2), tb, 0, stream>>>(Qb, Kb, Vt,
                                                           Cp0, Cp1, Ml2);
            merge_ctx<<<dim3(4096), tb, 0, stream>>>(Cp0, Cp1, Ml2, Ctx);
        }

        transpose_w<<<gTfull, tT, 0, stream>>>(wo, Wt, 0, hs);  // kills Cp0/Cp1
        gemm_bf16a<false, true><<<gG, tb, 0, stream>>>(Ctx, Wt, d_out, hs);
    } else {
        // ---------------- fallback: proven 48 MB pipeline ----------------
        bf16_t* R0 = (bf16_t*)ws;
        bf16_t* R1 = (bf16_t*)(ws + ((size_t)16 << 20));
        bf16_t* R2 = (bf16_t*)(ws + ((size_t)32 << 20));
        bf16_t* Kb  = R2;
        bf16_t* Vt  = R1;
        bf16_t* Ctx = R0;
        dim3 tG(512);
        dim3 gThalf(64, 32);
        dim3 gGfull(32, 16), gGhalf(16, 16);

        transpose_w<<<gTfull, tT, 0, stream>>>(wq, R0, 0, hs);
        gemm_nt<true, false, false><<<gGfull, tG, 0, stream>>>(hs, R0, Qb, 0, hs);
        transpose_w<<<gTfull, tT, 0, stream>>>(wk, R0, 0, hs);
        gemm_nt<true, false, false><<<gGfull, tG, 0, stream>>>(hs, R0, Kb, 0, hs);
        transpose_w<<<gThalf, tT, 0, stream>>>(wv, R0, 0, hs);
        gemm_nt<true, true, false><<<gGhalf, tG, 0, stream>>>(hs, R0, Vt, 0, hs);
        transpose_w<<<gThalf, tT, 0, stream>>>(wv, R0, 2048, hs);
        gemm_nt<true, true, false><<<gGhalf, tG, 0, stream>>>(hs, R0, Vt, 2048, hs);

        rope_qk<<<dim3(4096), tb, 0, stream>>>(Qb, Kb, pos);

        attn_kernel<<<dim3(16, 16), tb, 0, stream>>>(Qb, Kb, Vt, Ctx);

        transpose_w<<<gThalf, tT, 0, stream>>>(wo, R2, 0, hs);
        gemm_nt<false, false, true><<<gGhalf, tG, 0, stream>>>(Ctx, R2, d_out, 0, hs);
        transpose_w<<<gThalf, tT, 0, stream>>>(wo, R2, 2048, hs);
        gemm_nt<false, false, true><<<gGhalf, tG, 0, stream>>>(Ctx, R2, d_out, 2048, hs);
    }
}